// Round 15
// baseline (408.718 us; speedup 1.0000x reference)
//
#include <hip/hip_runtime.h>
#include <cstdint>

#define NP 200000
#define NA 100000
#define EW 300000
#define EC 300000
#define HID 128
#define FIN_P 256
#define FIN_A 128
#define NOUT 16
#define ATT_SCALE 0.17677669529663687f  // 1/sqrt(32)

#define NBP 1563   // ceil(NP/128)
#define NBA 782    // ceil(NA/128)

#define SCAN_N (2 * NP)
#define SCAN_BS 256
#define SCAN_ITEMS 4
#define SCAN_TILE 1024
#define SCAN_NB ((SCAN_N + SCAN_TILE - 1) / SCAN_TILE)  // 391

typedef short s8v __attribute__((ext_vector_type(8)));
typedef float f32x4 __attribute__((ext_vector_type(4)));
typedef unsigned short ushort_t;

// ---------- helpers ----------
__device__ __forceinline__ float gelu_f(float x) {
  return 0.5f * x * (1.0f + erff(x * 0.70710678118654752f));
}
__device__ __forceinline__ ushort_t f2bf(float f) {  // RNE
  unsigned u = __float_as_uint(f);
  return (ushort_t)((u + 0x7FFFu + ((u >> 16) & 1u)) >> 16);
}
__device__ __forceinline__ unsigned pack2bf(float a, float b) {
  return (unsigned)f2bf(a) | ((unsigned)f2bf(b) << 16);
}
__device__ __forceinline__ unsigned cvtpk(float a, float b) {
  unsigned r;
  asm("v_cvt_pk_bf16_f32 %0, %1, %2" : "=v"(r) : "v"(a), "v"(b));
  return r;
}
__device__ __forceinline__ float bflo(unsigned u) { return __uint_as_float(u << 16); }
__device__ __forceinline__ float bfhi(unsigned u) { return __uint_as_float(u & 0xFFFF0000u); }

// async global->LDS, 16B/lane; LDS dest = wave-uniform base + lane*16 (linear)
__device__ __forceinline__ void gl16(const void* g, void* l) {
  __builtin_amdgcn_global_load_lds(
      (const __attribute__((address_space(1))) void*)g,
      (__attribute__((address_space(3))) void*)l, 16, 0, 0);
}

// slot swizzle: slot s holds logical (row = s>>2, kg = (s&3) ^ s2(row));
// frag read for logical (row, kgl) -> phys = row*4 + (kgl ^ s2(row)).
__device__ __forceinline__ int s2row(int r) { return (r ^ (r >> 2)) & 3; }

// ---------- prep: weights->bf16 [n][k], epilogue Wcat (bf16), cnt zeroing ----------
__global__ void prep_all(
    const float* __restrict__ qw,  const float* __restrict__ qb,
    const float* __restrict__ kwp, const float* __restrict__ kbp, const float* __restrict__ arc,
    const float* __restrict__ vwp, const float* __restrict__ vbp, const float* __restrict__ mrc,
    const float* __restrict__ kwa, const float* __restrict__ kba, const float* __restrict__ arw,
    const float* __restrict__ vwa, const float* __restrict__ vba, const float* __restrict__ mrw,
    const float* __restrict__ lpw, const float* __restrict__ law,
    const float* __restrict__ aw, const float* __restrict__ ab,
    const float* __restrict__ skip, const float* __restrict__ W2, const float* __restrict__ b2,
    ushort_t* __restrict__ Wall, float* __restrict__ Ball,
    ushort_t* __restrict__ Wcatb, float* __restrict__ bo,
    int* __restrict__ cnt)
{
  const int b = blockIdx.x, tid = threadIdx.x;
  if (b == 0) {
    for (int idx = tid; idx < 16384; idx += 256) {
      int c = idx >> 7, r = idx & 127;
      Wall[idx] = f2bf(qw[r * 128 + c]);
    }
    for (int c = tid; c < 128; c += 256) Ball[c] = qb[c];
  } else if (b <= 4) {
    const float *W, *bias, *rel;
    switch (b) {
      case 1:  W = kwp; bias = kbp; rel = arc; break;
      case 2:  W = vwp; bias = vbp; rel = mrc; break;
      case 3:  W = kwa; bias = kba; rel = arw; break;
      default: W = vwa; bias = vba; rel = mrw; break;
    }
    for (int idx = tid; idx < 16384; idx += 256) {
      int c = idx >> 7, r = idx & 127, h = c >> 5, e = c & 31;
      float s = 0.f;
      #pragma unroll
      for (int d = 0; d < 32; ++d) s += W[r * 128 + h * 32 + d] * rel[h * 1024 + d * 32 + e];
      Wall[b * 16384 + idx] = f2bf(s);
    }
    for (int c = tid; c < 128; c += 256) {
      int h = c >> 5, e = c & 31;
      float s = 0.f;
      #pragma unroll
      for (int d = 0; d < 32; ++d) s += bias[h * 32 + d] * rel[h * 1024 + d * 32 + e];
      Ball[b * 128 + c] = s;
    }
  } else if (b == 5) {
    for (int idx = tid; idx < 16384; idx += 256) {
      int c = idx >> 7, r = idx & 127;
      Wall[5 * 16384 + idx] = f2bf(law[r * 128 + c]);
    }
  } else if (b == 6) {
    for (int idx = tid; idx < 32768; idx += 256) {
      int c = idx >> 8, r = idx & 255;
      Wall[6 * 16384 + idx] = f2bf(lpw[r * 128 + c]);
    }
  } else if (b == 7) {
    float beta = 1.0f / (1.0f + expf(-skip[0]));
    for (int idx = tid; idx < 4096; idx += 256) {
      int c = idx >> 8, k = idx & 255;
      float v;
      if (k < 128) {
        float s = 0.f;
        for (int j = 0; j < 128; ++j) s += aw[k * 128 + j] * W2[j * 16 + c];
        v = beta * s;
      } else {
        v = (1.0f - beta) * W2[(k - 128) * 16 + c];
      }
      Wcatb[c * 256 + k] = f2bf(v);
    }
    if (tid < 16) {
      float s = 0.f;
      for (int k = 0; k < 128; ++k) s += ab[k] * W2[k * 16 + tid];
      bo[tid] = beta * s + b2[tid];
    }
  } else {
    int chunk = SCAN_N / 8;
    int base = (b - 8) * chunk;
    for (int i = tid; i < chunk; i += 256) cnt[base + i] = 0;
  }
}

// ---------- fused GEMM main, 32 KB LDS: projection then q/kr/vr (A restaged per set) ----------
__global__ __launch_bounds__(256) void gemm_main(
    const float* __restrict__ xp, const float* __restrict__ xa,
    const ushort_t* __restrict__ Wall,
    const float* __restrict__ bp, const float* __restrict__ ba,
    const float* __restrict__ Ball,
    ushort_t* __restrict__ hpo, ushort_t* __restrict__ hao,
    ushort_t* __restrict__ qkv, ushort_t* __restrict__ kvw)
{
  __shared__ ushort_t As[8192];   // 16 KB (2 pages of 512 slots)
  __shared__ ushort_t Bs[8192];   // 16 KB
  const bool isP = blockIdx.x < NBP;
  const int bid = isP ? blockIdx.x : blockIdx.x - NBP;
  const float* A = isP ? xp : xa;
  const ushort_t* Wp = Wall + (isP ? 6 * 16384 : 5 * 16384);
  const float* biasp = isP ? bp : ba;
  ushort_t* Chp = isP ? hpo : hao;
  const int M = isP ? NP : NA;
  const int KT = isP ? 256 : 128;
  const int nt = KT >> 6;
  const int base_set = isP ? 0 : 3;
  const int nsets = isP ? 3 : 2;

  const int tid  = threadIdx.x;
  const int lane = tid & 63;
  const int wv   = tid >> 6;
  const int wr   = wv >> 1, wc = wv & 1;
  const int l15  = lane & 15, kgl = lane >> 4;
  const int s2l  = (l15 ^ (l15 >> 2)) & 3;
  const int row0 = bid * 128;

  const int r0 = tid >> 2, kgp = tid & 3;
  const int sk = kgp ^ s2row(r0);
  int g0 = row0 + r0;       if (g0 > M - 1) g0 = M - 1;
  int g1 = row0 + r0 + 64;  if (g1 > M - 1) g1 = M - 1;

  // ================= part 1: input projection (BK=64 phases) =================
  {
    const float* a0p = A + (size_t)g0 * KT + sk * 8;
    const float* a1p = A + (size_t)g1 * KT + sk * 8;
    const ushort_t* b0p = Wp + (size_t)r0 * KT + sk * 8;
    const ushort_t* b1p = Wp + (size_t)(r0 + 64) * KT + sk * 8;

    f32x4 acc[4][4];
    #pragma unroll
    for (int i = 0; i < 4; ++i)
      #pragma unroll
      for (int j = 0; j < 4; ++j) acc[i][j] = (f32x4){0.f, 0.f, 0.f, 0.f};

    for (int t = 0; t < nt; ++t) {
      const int kt = t * 64;
      gl16(b0p + kt,      &Bs[(size_t)tid * 8]);
      gl16(b1p + kt,      &Bs[(size_t)(tid + 256) * 8]);
      gl16(b0p + kt + 32, &Bs[(size_t)(tid + 512) * 8]);
      gl16(b1p + kt + 32, &Bs[(size_t)(tid + 768) * 8]);
      float4 fa0 = *(const float4*)(a0p + kt);
      float4 fa1 = *(const float4*)(a0p + kt + 4);
      float4 fa2 = *(const float4*)(a1p + kt);
      float4 fa3 = *(const float4*)(a1p + kt + 4);
      float4 fb0 = *(const float4*)(a0p + kt + 32);
      float4 fb1 = *(const float4*)(a0p + kt + 36);
      float4 fb2 = *(const float4*)(a1p + kt + 32);
      float4 fb3 = *(const float4*)(a1p + kt + 36);
      uint4 v;
      v.x = cvtpk(fa0.x, fa0.y); v.y = cvtpk(fa0.z, fa0.w);
      v.z = cvtpk(fa1.x, fa1.y); v.w = cvtpk(fa1.z, fa1.w);
      *(uint4*)&As[(size_t)tid * 8] = v;
      v.x = cvtpk(fa2.x, fa2.y); v.y = cvtpk(fa2.z, fa2.w);
      v.z = cvtpk(fa3.x, fa3.y); v.w = cvtpk(fa3.z, fa3.w);
      *(uint4*)&As[(size_t)(tid + 256) * 8] = v;
      v.x = cvtpk(fb0.x, fb0.y); v.y = cvtpk(fb0.z, fb0.w);
      v.z = cvtpk(fb1.x, fb1.y); v.w = cvtpk(fb1.z, fb1.w);
      *(uint4*)&As[(size_t)(tid + 512) * 8] = v;
      v.x = cvtpk(fb2.x, fb2.y); v.y = cvtpk(fb2.z, fb2.w);
      v.z = cvtpk(fb3.x, fb3.y); v.w = cvtpk(fb3.z, fb3.w);
      *(uint4*)&As[(size_t)(tid + 768) * 8] = v;
      __syncthreads();

      const s8v* As8 = (const s8v*)As;
      const s8v* Bs8 = (const s8v*)Bs;
      #pragma unroll
      for (int pg = 0; pg < 2; ++pg) {
        s8v af[4], bfv[4];
        #pragma unroll
        for (int i = 0; i < 4; ++i)
          af[i]  = As8[pg * 512 + (wr * 64 + i * 16 + l15) * 4 + (kgl ^ s2l)];
        #pragma unroll
        for (int j = 0; j < 4; ++j)
          bfv[j] = Bs8[pg * 512 + (wc * 64 + j * 16 + l15) * 4 + (kgl ^ s2l)];
        #pragma unroll
        for (int i = 0; i < 4; ++i)
          #pragma unroll
          for (int j = 0; j < 4; ++j)
            acc[i][j] = __builtin_amdgcn_mfma_f32_16x16x32_bf16(af[i], bfv[j], acc[i][j], 0, 0, 0);
      }
      __syncthreads();
    }

    float bv[4];
    #pragma unroll
    for (int j = 0; j < 4; ++j) bv[j] = biasp[wc * 64 + j * 16 + l15];
    #pragma unroll
    for (int i = 0; i < 4; ++i) {
      #pragma unroll
      for (int r = 0; r < 4; ++r) {
        int row = row0 + wr * 64 + i * 16 + kgl * 4 + r;
        if (row < M) {
          #pragma unroll
          for (int j = 0; j < 4; ++j) {
            float vv = acc[i][j][r] + bv[j];
            vv = fmaxf(vv, 0.f);
            Chp[(size_t)row * 128 + wc * 64 + j * 16 + l15] = f2bf(vv);
          }
        }
      }
    }
  }
  __syncthreads();   // drain hp stores to L2 (same XCD) before re-reading

  // ================= part 2: q / kr / vr — BK=64 phases, A restaged per set (L2-hot) =====
  {
    const ushort_t* a0h = Chp + (size_t)g0 * 128 + sk * 8;
    const ushort_t* a1h = Chp + (size_t)g1 * 128 + sk * 8;

    for (int si = 0; si < nsets; ++si) {
      const int set = base_set + si;
      const ushort_t* W = Wall + set * 16384;
      const float* bias = Ball + set * 128;
      ushort_t* C = isP ? (qkv + (size_t)set * NP * HID)
                        : (kvw + (size_t)(set - 3) * NA * HID);
      const ushort_t* b0p = W + (size_t)r0 * 128 + sk * 8;
      const ushort_t* b1p = W + (size_t)(r0 + 64) * 128 + sk * 8;

      f32x4 acc[4][4];
      #pragma unroll
      for (int i = 0; i < 4; ++i)
        #pragma unroll
        for (int j = 0; j < 4; ++j) acc[i][j] = (f32x4){0.f, 0.f, 0.f, 0.f};

      #pragma unroll
      for (int ph = 0; ph < 2; ++ph) {
        const int kt = ph * 64;
        gl16(a0h + kt,      &As[(size_t)tid * 8]);
        gl16(a1h + kt,      &As[(size_t)(tid + 256) * 8]);
        gl16(a0h + kt + 32, &As[(size_t)(tid + 512) * 8]);
        gl16(a1h + kt + 32, &As[(size_t)(tid + 768) * 8]);
        gl16(b0p + kt,      &Bs[(size_t)tid * 8]);
        gl16(b1p + kt,      &Bs[(size_t)(tid + 256) * 8]);
        gl16(b0p + kt + 32, &Bs[(size_t)(tid + 512) * 8]);
        gl16(b1p + kt + 32, &Bs[(size_t)(tid + 768) * 8]);
        __syncthreads();

        const s8v* As8 = (const s8v*)As;
        const s8v* Bs8 = (const s8v*)Bs;
        #pragma unroll
        for (int pg = 0; pg < 2; ++pg) {
          s8v af[4], bfv[4];
          #pragma unroll
          for (int i = 0; i < 4; ++i)
            af[i]  = As8[pg * 512 + (wr * 64 + i * 16 + l15) * 4 + (kgl ^ s2l)];
          #pragma unroll
          for (int j = 0; j < 4; ++j)
            bfv[j] = Bs8[pg * 512 + (wc * 64 + j * 16 + l15) * 4 + (kgl ^ s2l)];
          #pragma unroll
          for (int i = 0; i < 4; ++i)
            #pragma unroll
            for (int j = 0; j < 4; ++j)
              acc[i][j] = __builtin_amdgcn_mfma_f32_16x16x32_bf16(af[i], bfv[j], acc[i][j], 0, 0, 0);
        }
        __syncthreads();
      }

      float bv[4];
      #pragma unroll
      for (int j = 0; j < 4; ++j) bv[j] = bias[wc * 64 + j * 16 + l15];
      #pragma unroll
      for (int i = 0; i < 4; ++i) {
        #pragma unroll
        for (int r = 0; r < 4; ++r) {
          int row = row0 + wr * 64 + i * 16 + kgl * 4 + r;
          if (row < M) {
            #pragma unroll
            for (int j = 0; j < 4; ++j) {
              C[(size_t)row * 128 + wc * 64 + j * 16 + l15] = f2bf(acc[i][j][r] + bv[j]);
            }
          }
        }
      }
    }
  }
}

// ---------- CSR build ----------
__global__ void hist_k(const int* __restrict__ wdst, const int* __restrict__ cdst,
                       int* __restrict__ cnt)
{
  int t = blockIdx.x * blockDim.x + threadIdx.x;
  if (t < EW) atomicAdd(&cnt[wdst[t]], 1);
  if (t < EC) atomicAdd(&cnt[NP + cdst[t]], 1);
}

__global__ __launch_bounds__(SCAN_BS) void scan1(const int* __restrict__ cnt,
                                                 int* __restrict__ off,
                                                 int* __restrict__ bsum)
{
  __shared__ int sh[2][SCAN_BS];
  int tid = threadIdx.x;
  int base = blockIdx.x * SCAN_TILE + tid * SCAN_ITEMS;
  int v[SCAN_ITEMS]; int tsum = 0;
  #pragma unroll
  for (int i = 0; i < SCAN_ITEMS; ++i) {
    int idx = base + i;
    v[i] = (idx < SCAN_N) ? cnt[idx] : 0;
    tsum += v[i];
  }
  int p = 0;
  sh[0][tid] = tsum; __syncthreads();
  #pragma unroll
  for (int d = 1; d < SCAN_BS; d <<= 1) {
    int x = sh[p][tid] + ((tid >= d) ? sh[p][tid - d] : 0);
    sh[p ^ 1][tid] = x; __syncthreads(); p ^= 1;
  }
  int run = sh[p][tid] - tsum;
  #pragma unroll
  for (int i = 0; i < SCAN_ITEMS; ++i) {
    int idx = base + i;
    if (idx < SCAN_N) off[idx] = run;
    run += v[i];
  }
  if (tid == SCAN_BS - 1) bsum[blockIdx.x] = sh[p][tid];
}

__global__ __launch_bounds__(512) void scan2(int* __restrict__ bsum)
{
  __shared__ int sh[2][512];
  int tid = threadIdx.x;
  int v = (tid < SCAN_NB) ? bsum[tid] : 0;
  int p = 0;
  sh[0][tid] = v; __syncthreads();
  for (int d = 1; d < 512; d <<= 1) {
    int x = sh[p][tid] + ((tid >= d) ? sh[p][tid - d] : 0);
    sh[p ^ 1][tid] = x; __syncthreads(); p ^= 1;
  }
  if (tid < SCAN_NB) bsum[tid] = sh[p][tid] - v;
}

__global__ __launch_bounds__(SCAN_BS) void scan3(int* __restrict__ off, int* __restrict__ cur,
                                                 const int* __restrict__ bsum)
{
  int add = bsum[blockIdx.x];
  int base = blockIdx.x * SCAN_TILE + threadIdx.x;
  #pragma unroll
  for (int i = 0; i < SCAN_ITEMS; ++i) {
    int idx = base + i * SCAN_BS;
    if (idx < SCAN_N) { int t = off[idx] + add; off[idx] = t; cur[idx] = t; }
  }
  if (blockIdx.x == 0 && threadIdx.x == 0) off[SCAN_N] = EW + EC;
}

// esrc stores BYTE offsets (src * 256)
__global__ void fill_k(const int* __restrict__ wsrc, const int* __restrict__ wdst,
                       const int* __restrict__ csrc, const int* __restrict__ cdst,
                       int* __restrict__ cur, int* __restrict__ esrc)
{
  int t = blockIdx.x * blockDim.x + threadIdx.x;
  if (t < EW) { int p = atomicAdd(&cur[wdst[t]], 1); esrc[p] = wsrc[t] << 8; }
  if (t < EC) { int p = atomicAdd(&cur[NP + cdst[t]], 1); esrc[p] = csrc[t] << 8; }
}

// ---------- fused per-node attention: 16 lanes/node, prefetch + batched gathers ----------
__global__ __launch_bounds__(256) void node_attn(
    const int* __restrict__ off, const int* __restrict__ esrc,
    const ushort_t* __restrict__ q,
    const ushort_t* __restrict__ kr_w, const ushort_t* __restrict__ vr_w,
    const ushort_t* __restrict__ kr_c, const ushort_t* __restrict__ vr_c,
    const float* __restrict__ p_rel_w, const float* __restrict__ p_rel_c,
    ushort_t* __restrict__ out_p)
{
  int gid = blockIdx.x * blockDim.x + threadIdx.x;
  int node = gid >> 4;
  int l16 = gid & 15;
  int h = l16 >> 2;
  unsigned loff = (unsigned)(l16 * 16);

  int eb0 = off[node],      ee0 = off[node + 1];
  int eb1 = off[NP + node], ee1 = off[NP + node + 1];

  uint4 qv = *(const uint4*)(q + (size_t)node * HID + l16 * 8);

  // cross-relation first-edge prefetch (concurrent with q load)
  int pi0 = (eb0 < ee0) ? eb0 : 0;
  int pi1 = (eb1 < ee1) ? eb1 : 0;
  unsigned pb0 = (unsigned)esrc[pi0] + loff;
  unsigned pb1 = (unsigned)esrc[pi1] + loff;
  uint4 pk[2], pv[2];
  pk[0] = *(const uint4*)((const char*)kr_w + pb0);
  pv[0] = *(const uint4*)((const char*)vr_w + pb0);
  pk[1] = *(const uint4*)((const char*)kr_c + pb1);
  pv[1] = *(const uint4*)((const char*)vr_c + pb1);

  float qf[8];
  {
    const unsigned* pq = (const unsigned*)&qv;
    #pragma unroll
    for (int w = 0; w < 4; ++w) { qf[2 * w] = bflo(pq[w]); qf[2 * w + 1] = bfhi(pq[w]); }
  }
  float prw = p_rel_w[h] * ATT_SCALE;
  float prc = p_rel_c[h] * ATT_SCALE;

  float t[8];
  #pragma unroll
  for (int i = 0; i < 8; ++i) t[i] = 0.f;

  #pragma unroll
  for (int r = 0; r < 2; ++r) {
    const char* krb = (const char*)((r == 0) ? kr_w : kr_c);
    const char* vrb = (const char*)((r == 0) ? vr_w : vr_c);
    float prr = (r == 0) ? prw : prc;
    int eb = (r == 0) ? eb0 : eb1;
    int ee = (r == 0) ? ee0 : ee1;

    float s = 0.f;
    float A[8];
    #pragma unroll
    for (int i = 0; i < 8; ++i) A[i] = 0.f;

    int e = eb;
    if (e < ee) {  // consume prefetched first edge
      const unsigned* k8 = (const unsigned*)&pk[r];
      const unsigned* v8 = (const unsigned*)&pv[r];
      float d = 0.f;
      #pragma unroll
      for (int w = 0; w < 4; ++w) {
        d = fmaf(qf[2 * w], bflo(k8[w]), d);
        d = fmaf(qf[2 * w + 1], bfhi(k8[w]), d);
      }
      d += __shfl_xor(d, 1);
      d += __shfl_xor(d, 2);
      float p = __expf(d * prr);
      s += p;
      #pragma unroll
      for (int w = 0; w < 4; ++w) {
        A[2 * w]     = fmaf(p, bflo(v8[w]), A[2 * w]);
        A[2 * w + 1] = fmaf(p, bfhi(v8[w]), A[2 * w + 1]);
      }
      ++e;
    }
    // batched remainder: 4 edges per iteration, 8 concurrent K/V gathers
    while (e < ee) {
      int n = ee - e;
      unsigned kb0 = (unsigned)esrc[e] + loff;
      unsigned kb1 = (unsigned)esrc[(n > 1) ? e + 1 : e] + loff;
      unsigned kb2 = (unsigned)esrc[(n > 2) ? e + 2 : e] + loff;
      unsigned kb3 = (unsigned)esrc[(n > 3) ? e + 3 : e] + loff;
      uint4 kv0 = *(const uint4*)(krb + kb0);
      uint4 vv0 = *(const uint4*)(vrb + kb0);
      uint4 kv1 = *(const uint4*)(krb + kb1);
      uint4 vv1 = *(const uint4*)(vrb + kb1);
      uint4 kv2 = *(const uint4*)(krb + kb2);
      uint4 vv2 = *(const uint4*)(vrb + kb2);
      uint4 kv3 = *(const uint4*)(krb + kb3);
      uint4 vv3 = *(const uint4*)(vrb + kb3);
      const uint4* kvs[4] = {&kv0, &kv1, &kv2, &kv3};
      const uint4* vvs[4] = {&vv0, &vv1, &vv2, &vv3};
      // 4 independent dot/shfl chains
      float dd[4];
      #pragma unroll
      for (int i = 0; i < 4; ++i) {
        const unsigned* k8 = (const unsigned*)kvs[i];
        float d = 0.f;
        #pragma unroll
        for (int w = 0; w < 4; ++w) {
          d = fmaf(qf[2 * w], bflo(k8[w]), d);
          d = fmaf(qf[2 * w + 1], bfhi(k8[w]), d);
        }
        d += __shfl_xor(d, 1);
        d += __shfl_xor(d, 2);
        dd[i] = d;
      }
      #pragma unroll
      for (int i = 0; i < 4; ++i) {
        if (i < n) {
          float p = __expf(dd[i] * prr);
          s += p;
          const unsigned* v8 = (const unsigned*)vvs[i];
          #pragma unroll
          for (int w = 0; w < 4; ++w) {
            A[2 * w]     = fmaf(p, bflo(v8[w]), A[2 * w]);
            A[2 * w + 1] = fmaf(p, bfhi(v8[w]), A[2 * w + 1]);
          }
        }
      }
      e += 4;
    }
    float inv = 1.0f / (s + 1e-16f);
    #pragma unroll
    for (int i = 0; i < 8; ++i) t[i] = fmaf(A[i], inv, t[i]);
  }

  uint4 o;
  unsigned* po = (unsigned*)&o;
  #pragma unroll
  for (int w = 0; w < 4; ++w) po[w] = pack2bf(t[2 * w], t[2 * w + 1]);
  *(uint4*)(out_p + (size_t)node * HID + l16 * 8) = o;
}

// ---------- MFMA epilogue: out = [gelu(outp), hp] @ Wcat^T + bo ----------
__global__ __launch_bounds__(256) void epilogue_mfma(
    const ushort_t* __restrict__ out_p, const ushort_t* __restrict__ hp,
    const ushort_t* __restrict__ Wcatb, const float* __restrict__ bo,
    float* __restrict__ out)
{
  __shared__ ushort_t As[4096];   // 512 slots x 8 = 8 KB
  const int tid  = threadIdx.x;
  const int lane = tid & 63;
  const int wv   = tid >> 6;
  const int l15  = lane & 15, kgl = lane >> 4;
  const int s2l  = (l15 ^ (l15 >> 2)) & 3;
  const int row0 = blockIdx.x * 128;

  const int r0 = tid >> 2, kgp = tid & 3;
  const int sk = kgp ^ s2row(r0);
  int g0 = row0 + r0;       if (g0 > NP - 1) g0 = NP - 1;
  int g1 = row0 + r0 + 64;  if (g1 > NP - 1) g1 = NP - 1;

  s8v bfr[8];
  #pragma unroll
  for (int ks = 0; ks < 8; ++ks)
    bfr[ks] = *(const s8v*)(Wcatb + (size_t)l15 * 256 + ks * 32 + kgl * 8);
  float bo_l = bo[l15];

  f32x4 acc[2];
  acc[0] = (f32x4){0.f, 0.f, 0.f, 0.f};
  acc[1] = (f32x4){0.f, 0.f, 0.f, 0.f};

  #pragma unroll
  for (int ph = 0; ph < 8; ++ph) {
    if (ph < 4) {
      const int kt = ph * 32;
      uint4 v0 = *(const uint4*)(out_p + (size_t)g0 * 128 + kt + sk * 8);
      uint4 v1 = *(const uint4*)(out_p + (size_t)g1 * 128 + kt + sk * 8);
      unsigned* p0 = (unsigned*)&v0;
      unsigned* p1 = (unsigned*)&v1;
      #pragma unroll
      for (int w = 0; w < 4; ++w) {
        p0[w] = cvtpk(gelu_f(bflo(p0[w])), gelu_f(bfhi(p0[w])));
        p1[w] = cvtpk(gelu_f(bflo(p1[w])), gelu_f(bfhi(p1[w])));
      }
      *(uint4*)&As[(size_t)tid * 8] = v0;
      *(uint4*)&As[(size_t)(tid + 256) * 8] = v1;
    } else {
      const int kt = (ph - 4) * 32;
      gl16(hp + (size_t)g0 * 128 + kt + sk * 8, &As[(size_t)tid * 8]);
      gl16(hp + (size_t)g1 * 128 + kt + sk * 8, &As[(size_t)(tid + 256) * 8]);
    }
    __syncthreads();

    const s8v* As8 = (const s8v*)As;
    s8v af0 = As8[(wv * 32 + l15) * 4 + (kgl ^ s2l)];
    s8v af1 = As8[(wv * 32 + 16 + l15) * 4 + (kgl ^ s2l)];
    acc[0] = __builtin_amdgcn_mfma_f32_16x16x32_bf16(af0, bfr[ph], acc[0], 0, 0, 0);
    acc[1] = __builtin_amdgcn_mfma_f32_16x16x32_bf16(af1, bfr[ph], acc[1], 0, 0, 0);
    __syncthreads();
  }

  #pragma unroll
  for (int i = 0; i < 2; ++i) {
    #pragma unroll
    for (int r = 0; r < 4; ++r) {
      int row = row0 + wv * 32 + i * 16 + kgl * 4 + r;
      if (row < NP) out[(size_t)row * NOUT + l15] = acc[i][r] + bo_l;
    }
  }
}

// ---------- launch ----------
extern "C" void kernel_launch(void* const* d_in, const int* in_sizes, int n_in,
                              void* d_out, int out_size, void* d_ws, size_t ws_size,
                              hipStream_t stream)
{
  (void)in_sizes; (void)n_in; (void)out_size; (void)ws_size;
  const float* x_paper      = (const float*)d_in[0];
  const float* x_author     = (const float*)d_in[1];
  const int*   writes_src   = (const int*)d_in[2];
  const int*   writes_dst   = (const int*)d_in[3];
  const int*   cites_src    = (const int*)d_in[4];
  const int*   cites_dst    = (const int*)d_in[5];
  const float* lin_paper_w  = (const float*)d_in[6];
  const float* lin_paper_b  = (const float*)d_in[7];
  const float* lin_author_w = (const float*)d_in[8];
  const float* lin_author_b = (const float*)d_in[9];
  const float* lin_out_w    = (const float*)d_in[10];
  const float* lin_out_b    = (const float*)d_in[11];
  const float* k_w_paper    = (const float*)d_in[12];
  const float* k_b_paper    = (const float*)d_in[13];
  const float* q_w_paper    = (const float*)d_in[14];
  const float* q_b_paper    = (const float*)d_in[15];
  const float* v_w_paper    = (const float*)d_in[16];
  const float* v_b_paper    = (const float*)d_in[17];
  const float* a_w_paper    = (const float*)d_in[18];
  const float* a_b_paper    = (const float*)d_in[19];
  const float* skip_paper   = (const float*)d_in[20];
  const float* k_w_author   = (const float*)d_in[21];
  const float* k_b_author   = (const float*)d_in[22];
  const float* v_w_author   = (const float*)d_in[25];
  const float* v_b_author   = (const float*)d_in[26];
  const float* a_rel_writes = (const float*)d_in[30];
  const float* m_rel_writes = (const float*)d_in[31];
  const float* p_rel_writes = (const float*)d_in[32];
  const float* a_rel_cites  = (const float*)d_in[33];
  const float* m_rel_cites  = (const float*)d_in[34];
  const float* p_rel_cites  = (const float*)d_in[35];

  float* ws = (float*)d_ws;
  size_t off_f = 0;
  auto nxt = [&](size_t nfloats) { float* p = ws + off_f; off_f += nfloats; return p; };
  ushort_t* hp    = (ushort_t*)nxt((size_t)NP * 64);
  ushort_t* ha    = (ushort_t*)nxt((size_t)NA * 64);
  ushort_t* qkv   = (ushort_t*)nxt((size_t)3 * NP * 64);
  ushort_t* kvw   = (ushort_t*)nxt((size_t)2 * NA * 64);
  ushort_t* outp  = (ushort_t*)nxt((size_t)NP * 64);
  int*      cnt   = (int*)nxt(SCAN_N);
  int*      offs  = (int*)nxt(SCAN_N + 2);
  int*      cur   = (int*)nxt(SCAN_N);
  int*      esrc  = (int*)nxt(EW + EC);
  int*      bsum  = (int*)nxt(512);
  ushort_t* Wall  = (ushort_t*)nxt(65536);
  float*    Ball  = nxt(5 * 128);
  ushort_t* Wcatb = (ushort_t*)nxt(2048);   // 4096 bf16
  float*    bo    = nxt(16);

  ushort_t* q_p  = qkv;
  ushort_t* kr_c = qkv + (size_t)NP * HID;
  ushort_t* vr_c = qkv + (size_t)2 * NP * HID;
  ushort_t* kr_w = kvw;
  ushort_t* vr_w = kvw + (size_t)NA * HID;

  prep_all<<<16, 256, 0, stream>>>(q_w_paper, q_b_paper,
                                   k_w_paper, k_b_paper, a_rel_cites,
                                   v_w_paper, v_b_paper, m_rel_cites,
                                   k_w_author, k_b_author, a_rel_writes,
                                   v_w_author, v_b_author, m_rel_writes,
                                   lin_paper_w, lin_author_w,
                                   a_w_paper, a_b_paper, skip_paper, lin_out_w, lin_out_b,
                                   Wall, Ball, Wcatb, bo, cnt);

  hist_k<<<(300000 + 255) / 256, 256, 0, stream>>>(writes_dst, cites_dst, cnt);
  scan1<<<SCAN_NB, SCAN_BS, 0, stream>>>(cnt, offs, bsum);
  scan2<<<1, 512, 0, stream>>>(bsum);
  scan3<<<SCAN_NB, SCAN_BS, 0, stream>>>(offs, cur, bsum);
  fill_k<<<(300000 + 255) / 256, 256, 0, stream>>>(writes_src, writes_dst,
                                                   cites_src, cites_dst, cur, esrc);

  gemm_main<<<NBP + NBA, 256, 0, stream>>>(x_paper, x_author, Wall,
                                           lin_paper_b, lin_author_b, Ball,
                                           hp, ha, qkv, kvw);

  node_attn<<<(NP * 16) / 256, 256, 0, stream>>>(
      offs, esrc, q_p, kr_w, vr_w, kr_c, vr_c, p_rel_writes, p_rel_cites, outp);

  epilogue_mfma<<<NBP, 256, 0, stream>>>(outp, hp, Wcatb, bo, (float*)d_out);
}

// Round 16
// 381.676 us; speedup vs baseline: 1.0708x; 1.0708x over previous
//
#include <hip/hip_runtime.h>
#include <cstdint>

#define NP 200000
#define NA 100000
#define EW 300000
#define EC 300000
#define HID 128
#define FIN_P 256
#define FIN_A 128
#define NOUT 16
#define ATT_SCALE 0.17677669529663687f  // 1/sqrt(32)

#define NBP 1563   // ceil(NP/128)
#define NBA 782    // ceil(NA/128)

#define SCAN_N (2 * NP)
#define SCAN_BS 256
#define SCAN_ITEMS 4
#define SCAN_TILE 1024
#define SCAN_NB ((SCAN_N + SCAN_TILE - 1) / SCAN_TILE)  // 391

typedef short s8v __attribute__((ext_vector_type(8)));
typedef float f32x4 __attribute__((ext_vector_type(4)));
typedef unsigned short ushort_t;

// ---------- helpers ----------
__device__ __forceinline__ float gelu_f(float x) {
  return 0.5f * x * (1.0f + erff(x * 0.70710678118654752f));
}
__device__ __forceinline__ ushort_t f2bf(float f) {  // RNE
  unsigned u = __float_as_uint(f);
  return (ushort_t)((u + 0x7FFFu + ((u >> 16) & 1u)) >> 16);
}
__device__ __forceinline__ unsigned pack2bf(float a, float b) {
  return (unsigned)f2bf(a) | ((unsigned)f2bf(b) << 16);
}
__device__ __forceinline__ unsigned cvtpk(float a, float b) {
  unsigned r;
  asm("v_cvt_pk_bf16_f32 %0, %1, %2" : "=v"(r) : "v"(a), "v"(b));
  return r;
}
__device__ __forceinline__ float bflo(unsigned u) { return __uint_as_float(u << 16); }
__device__ __forceinline__ float bfhi(unsigned u) { return __uint_as_float(u & 0xFFFF0000u); }

// async global->LDS, 16B/lane; LDS dest = wave-uniform base + lane*16 (linear)
__device__ __forceinline__ void gl16(const void* g, void* l) {
  __builtin_amdgcn_global_load_lds(
      (const __attribute__((address_space(1))) void*)g,
      (__attribute__((address_space(3))) void*)l, 16, 0, 0);
}

// slot swizzle: slot s holds logical (row = s>>2, kg = (s&3) ^ s2(row));
// frag read for logical (row, kgl) -> phys = row*4 + (kgl ^ s2(row)).
__device__ __forceinline__ int s2row(int r) { return (r ^ (r >> 2)) & 3; }

// ---------- prep: weights->bf16 [n][k], epilogue Wcat (bf16), cnt zeroing ----------
__global__ void prep_all(
    const float* __restrict__ qw,  const float* __restrict__ qb,
    const float* __restrict__ kwp, const float* __restrict__ kbp, const float* __restrict__ arc,
    const float* __restrict__ vwp, const float* __restrict__ vbp, const float* __restrict__ mrc,
    const float* __restrict__ kwa, const float* __restrict__ kba, const float* __restrict__ arw,
    const float* __restrict__ vwa, const float* __restrict__ vba, const float* __restrict__ mrw,
    const float* __restrict__ lpw, const float* __restrict__ law,
    const float* __restrict__ aw, const float* __restrict__ ab,
    const float* __restrict__ skip, const float* __restrict__ W2, const float* __restrict__ b2,
    ushort_t* __restrict__ Wall, float* __restrict__ Ball,
    ushort_t* __restrict__ Wcatb, float* __restrict__ bo,
    int* __restrict__ cnt)
{
  const int b = blockIdx.x, tid = threadIdx.x;
  if (b == 0) {
    for (int idx = tid; idx < 16384; idx += 256) {
      int c = idx >> 7, r = idx & 127;
      Wall[idx] = f2bf(qw[r * 128 + c]);
    }
    for (int c = tid; c < 128; c += 256) Ball[c] = qb[c];
  } else if (b <= 4) {
    const float *W, *bias, *rel;
    switch (b) {
      case 1:  W = kwp; bias = kbp; rel = arc; break;
      case 2:  W = vwp; bias = vbp; rel = mrc; break;
      case 3:  W = kwa; bias = kba; rel = arw; break;
      default: W = vwa; bias = vba; rel = mrw; break;
    }
    for (int idx = tid; idx < 16384; idx += 256) {
      int c = idx >> 7, r = idx & 127, h = c >> 5, e = c & 31;
      float s = 0.f;
      #pragma unroll
      for (int d = 0; d < 32; ++d) s += W[r * 128 + h * 32 + d] * rel[h * 1024 + d * 32 + e];
      Wall[b * 16384 + idx] = f2bf(s);
    }
    for (int c = tid; c < 128; c += 256) {
      int h = c >> 5, e = c & 31;
      float s = 0.f;
      #pragma unroll
      for (int d = 0; d < 32; ++d) s += bias[h * 32 + d] * rel[h * 1024 + d * 32 + e];
      Ball[b * 128 + c] = s;
    }
  } else if (b == 5) {
    for (int idx = tid; idx < 16384; idx += 256) {
      int c = idx >> 7, r = idx & 127;
      Wall[5 * 16384 + idx] = f2bf(law[r * 128 + c]);
    }
  } else if (b == 6) {
    for (int idx = tid; idx < 32768; idx += 256) {
      int c = idx >> 8, r = idx & 255;
      Wall[6 * 16384 + idx] = f2bf(lpw[r * 128 + c]);
    }
  } else if (b == 7) {
    float beta = 1.0f / (1.0f + expf(-skip[0]));
    for (int idx = tid; idx < 4096; idx += 256) {
      int c = idx >> 8, k = idx & 255;
      float v;
      if (k < 128) {
        float s = 0.f;
        for (int j = 0; j < 128; ++j) s += aw[k * 128 + j] * W2[j * 16 + c];
        v = beta * s;
      } else {
        v = (1.0f - beta) * W2[(k - 128) * 16 + c];
      }
      Wcatb[c * 256 + k] = f2bf(v);
    }
    if (tid < 16) {
      float s = 0.f;
      for (int k = 0; k < 128; ++k) s += ab[k] * W2[k * 16 + tid];
      bo[tid] = beta * s + b2[tid];
    }
  } else {
    int chunk = SCAN_N / 8;
    int base = (b - 8) * chunk;
    for (int i = tid; i < chunk; i += 256) cnt[base + i] = 0;
  }
}

// ---------- fused GEMM main (r14-proven): projection then q/kr/vr from A-resident LDS ----------
__global__ __launch_bounds__(256) void gemm_main(
    const float* __restrict__ xp, const float* __restrict__ xa,
    const ushort_t* __restrict__ Wall,
    const float* __restrict__ bp, const float* __restrict__ ba,
    const float* __restrict__ Ball,
    ushort_t* __restrict__ hpo, ushort_t* __restrict__ hao,
    ushort_t* __restrict__ qkv, ushort_t* __restrict__ kvw)
{
  __shared__ ushort_t As[16384];   // 32 KB (part1: pages 0-1; part2: pages 0-3)
  __shared__ ushort_t Bs[16384];   // 32 KB
  const bool isP = blockIdx.x < NBP;
  const int bid = isP ? blockIdx.x : blockIdx.x - NBP;
  const float* A = isP ? xp : xa;
  const ushort_t* Wp = Wall + (isP ? 6 * 16384 : 5 * 16384);
  const float* biasp = isP ? bp : ba;
  ushort_t* Chp = isP ? hpo : hao;
  const int M = isP ? NP : NA;
  const int KT = isP ? 256 : 128;
  const int nt = KT >> 6;
  const int base_set = isP ? 0 : 3;
  const int nsets = isP ? 3 : 2;

  const int tid  = threadIdx.x;
  const int lane = tid & 63;
  const int wv   = tid >> 6;
  const int wr   = wv >> 1, wc = wv & 1;
  const int l15  = lane & 15, kgl = lane >> 4;
  const int s2l  = (l15 ^ (l15 >> 2)) & 3;
  const int row0 = bid * 128;

  const int r0 = tid >> 2, kgp = tid & 3;
  const int sk = kgp ^ s2row(r0);
  int g0 = row0 + r0;       if (g0 > M - 1) g0 = M - 1;
  int g1 = row0 + r0 + 64;  if (g1 > M - 1) g1 = M - 1;

  // ================= part 1: input projection (BK=64 phases) =================
  {
    const float* a0p = A + (size_t)g0 * KT + sk * 8;
    const float* a1p = A + (size_t)g1 * KT + sk * 8;
    const ushort_t* b0p = Wp + (size_t)r0 * KT + sk * 8;
    const ushort_t* b1p = Wp + (size_t)(r0 + 64) * KT + sk * 8;

    f32x4 acc[4][4];
    #pragma unroll
    for (int i = 0; i < 4; ++i)
      #pragma unroll
      for (int j = 0; j < 4; ++j) acc[i][j] = (f32x4){0.f, 0.f, 0.f, 0.f};

    for (int t = 0; t < nt; ++t) {
      const int kt = t * 64;
      gl16(b0p + kt,      &Bs[(size_t)tid * 8]);
      gl16(b1p + kt,      &Bs[(size_t)(tid + 256) * 8]);
      gl16(b0p + kt + 32, &Bs[(size_t)(tid + 512) * 8]);
      gl16(b1p + kt + 32, &Bs[(size_t)(tid + 768) * 8]);
      float4 fa0 = *(const float4*)(a0p + kt);
      float4 fa1 = *(const float4*)(a0p + kt + 4);
      float4 fa2 = *(const float4*)(a1p + kt);
      float4 fa3 = *(const float4*)(a1p + kt + 4);
      float4 fb0 = *(const float4*)(a0p + kt + 32);
      float4 fb1 = *(const float4*)(a0p + kt + 36);
      float4 fb2 = *(const float4*)(a1p + kt + 32);
      float4 fb3 = *(const float4*)(a1p + kt + 36);
      uint4 v;
      v.x = cvtpk(fa0.x, fa0.y); v.y = cvtpk(fa0.z, fa0.w);
      v.z = cvtpk(fa1.x, fa1.y); v.w = cvtpk(fa1.z, fa1.w);
      *(uint4*)&As[(size_t)tid * 8] = v;
      v.x = cvtpk(fa2.x, fa2.y); v.y = cvtpk(fa2.z, fa2.w);
      v.z = cvtpk(fa3.x, fa3.y); v.w = cvtpk(fa3.z, fa3.w);
      *(uint4*)&As[(size_t)(tid + 256) * 8] = v;
      v.x = cvtpk(fb0.x, fb0.y); v.y = cvtpk(fb0.z, fb0.w);
      v.z = cvtpk(fb1.x, fb1.y); v.w = cvtpk(fb1.z, fb1.w);
      *(uint4*)&As[(size_t)(tid + 512) * 8] = v;
      v.x = cvtpk(fb2.x, fb2.y); v.y = cvtpk(fb2.z, fb2.w);
      v.z = cvtpk(fb3.x, fb3.y); v.w = cvtpk(fb3.z, fb3.w);
      *(uint4*)&As[(size_t)(tid + 768) * 8] = v;
      __syncthreads();

      const s8v* As8 = (const s8v*)As;
      const s8v* Bs8 = (const s8v*)Bs;
      #pragma unroll
      for (int pg = 0; pg < 2; ++pg) {
        s8v af[4], bfv[4];
        #pragma unroll
        for (int i = 0; i < 4; ++i)
          af[i]  = As8[pg * 512 + (wr * 64 + i * 16 + l15) * 4 + (kgl ^ s2l)];
        #pragma unroll
        for (int j = 0; j < 4; ++j)
          bfv[j] = Bs8[pg * 512 + (wc * 64 + j * 16 + l15) * 4 + (kgl ^ s2l)];
        #pragma unroll
        for (int i = 0; i < 4; ++i)
          #pragma unroll
          for (int j = 0; j < 4; ++j)
            acc[i][j] = __builtin_amdgcn_mfma_f32_16x16x32_bf16(af[i], bfv[j], acc[i][j], 0, 0, 0);
      }
      __syncthreads();
    }

    float bv[4];
    #pragma unroll
    for (int j = 0; j < 4; ++j) bv[j] = biasp[wc * 64 + j * 16 + l15];
    #pragma unroll
    for (int i = 0; i < 4; ++i) {
      #pragma unroll
      for (int r = 0; r < 4; ++r) {
        int row = row0 + wr * 64 + i * 16 + kgl * 4 + r;
        if (row < M) {
          #pragma unroll
          for (int j = 0; j < 4; ++j) {
            float vv = acc[i][j][r] + bv[j];
            vv = fmaxf(vv, 0.f);
            Chp[(size_t)row * 128 + wc * 64 + j * 16 + l15] = f2bf(vv);
          }
        }
      }
    }
  }
  __syncthreads();   // drain hp stores to L2 (same XCD) + free LDS

  // ================= part 2: q / kr / vr from L2-hot hp tile (A resident) =================
  {
    const ushort_t* a0h = Chp + (size_t)g0 * 128 + sk * 8;
    const ushort_t* a1h = Chp + (size_t)g1 * 128 + sk * 8;
    #pragma unroll
    for (int t = 0; t < 4; ++t) {
      gl16(a0h + t * 32, &As[((size_t)t * 512 + tid) * 8]);
      gl16(a1h + t * 32, &As[((size_t)t * 512 + tid + 256) * 8]);
    }

    for (int si = 0; si < nsets; ++si) {
      const int set = base_set + si;
      const ushort_t* W = Wall + set * 16384;
      const float* bias = Ball + set * 128;
      ushort_t* C = isP ? (qkv + (size_t)set * NP * HID)
                        : (kvw + (size_t)(set - 3) * NA * HID);
      const ushort_t* b0p = W + (size_t)r0 * 128 + sk * 8;
      const ushort_t* b1p = W + (size_t)(r0 + 64) * 128 + sk * 8;
      #pragma unroll
      for (int t = 0; t < 4; ++t) {
        gl16(b0p + t * 32, &Bs[((size_t)t * 512 + tid) * 8]);
        gl16(b1p + t * 32, &Bs[((size_t)t * 512 + tid + 256) * 8]);
      }
      __syncthreads();

      f32x4 acc[4][4];
      #pragma unroll
      for (int i = 0; i < 4; ++i)
        #pragma unroll
        for (int j = 0; j < 4; ++j) acc[i][j] = (f32x4){0.f, 0.f, 0.f, 0.f};

      const s8v* As8 = (const s8v*)As;
      const s8v* Bs8 = (const s8v*)Bs;
      #pragma unroll
      for (int t = 0; t < 4; ++t) {
        s8v af[4], bfv[4];
        #pragma unroll
        for (int i = 0; i < 4; ++i)
          af[i]  = As8[t * 512 + (wr * 64 + i * 16 + l15) * 4 + (kgl ^ s2l)];
        #pragma unroll
        for (int j = 0; j < 4; ++j)
          bfv[j] = Bs8[t * 512 + (wc * 64 + j * 16 + l15) * 4 + (kgl ^ s2l)];
        #pragma unroll
        for (int i = 0; i < 4; ++i)
          #pragma unroll
          for (int j = 0; j < 4; ++j)
            acc[i][j] = __builtin_amdgcn_mfma_f32_16x16x32_bf16(af[i], bfv[j], acc[i][j], 0, 0, 0);
      }

      float bv[4];
      #pragma unroll
      for (int j = 0; j < 4; ++j) bv[j] = bias[wc * 64 + j * 16 + l15];
      #pragma unroll
      for (int i = 0; i < 4; ++i) {
        #pragma unroll
        for (int r = 0; r < 4; ++r) {
          int row = row0 + wr * 64 + i * 16 + kgl * 4 + r;
          if (row < M) {
            #pragma unroll
            for (int j = 0; j < 4; ++j) {
              C[(size_t)row * 128 + wc * 64 + j * 16 + l15] = f2bf(acc[i][j][r] + bv[j]);
            }
          }
        }
      }
      __syncthreads();
    }
  }
}

// ---------- CSR build ----------
__global__ void hist_k(const int* __restrict__ wdst, const int* __restrict__ cdst,
                       int* __restrict__ cnt)
{
  int t = blockIdx.x * blockDim.x + threadIdx.x;
  if (t < EW) atomicAdd(&cnt[wdst[t]], 1);
  if (t < EC) atomicAdd(&cnt[NP + cdst[t]], 1);
}

__global__ __launch_bounds__(SCAN_BS) void scan1(const int* __restrict__ cnt,
                                                 int* __restrict__ off,
                                                 int* __restrict__ bsum)
{
  __shared__ int sh[2][SCAN_BS];
  int tid = threadIdx.x;
  int base = blockIdx.x * SCAN_TILE + tid * SCAN_ITEMS;
  int v[SCAN_ITEMS]; int tsum = 0;
  #pragma unroll
  for (int i = 0; i < SCAN_ITEMS; ++i) {
    int idx = base + i;
    v[i] = (idx < SCAN_N) ? cnt[idx] : 0;
    tsum += v[i];
  }
  int p = 0;
  sh[0][tid] = tsum; __syncthreads();
  #pragma unroll
  for (int d = 1; d < SCAN_BS; d <<= 1) {
    int x = sh[p][tid] + ((tid >= d) ? sh[p][tid - d] : 0);
    sh[p ^ 1][tid] = x; __syncthreads(); p ^= 1;
  }
  int run = sh[p][tid] - tsum;
  #pragma unroll
  for (int i = 0; i < SCAN_ITEMS; ++i) {
    int idx = base + i;
    if (idx < SCAN_N) off[idx] = run;
    run += v[i];
  }
  if (tid == SCAN_BS - 1) bsum[blockIdx.x] = sh[p][tid];
}

__global__ __launch_bounds__(512) void scan2(int* __restrict__ bsum)
{
  __shared__ int sh[2][512];
  int tid = threadIdx.x;
  int v = (tid < SCAN_NB) ? bsum[tid] : 0;
  int p = 0;
  sh[0][tid] = v; __syncthreads();
  for (int d = 1; d < 512; d <<= 1) {
    int x = sh[p][tid] + ((tid >= d) ? sh[p][tid - d] : 0);
    sh[p ^ 1][tid] = x; __syncthreads(); p ^= 1;
  }
  if (tid < SCAN_NB) bsum[tid] = sh[p][tid] - v;
}

__global__ __launch_bounds__(SCAN_BS) void scan3(int* __restrict__ off, int* __restrict__ cur,
                                                 const int* __restrict__ bsum)
{
  int add = bsum[blockIdx.x];
  int base = blockIdx.x * SCAN_TILE + threadIdx.x;
  #pragma unroll
  for (int i = 0; i < SCAN_ITEMS; ++i) {
    int idx = base + i * SCAN_BS;
    if (idx < SCAN_N) { int t = off[idx] + add; off[idx] = t; cur[idx] = t; }
  }
  if (blockIdx.x == 0 && threadIdx.x == 0) off[SCAN_N] = EW + EC;
}

// esrc stores BYTE offsets (src * 256)
__global__ void fill_k(const int* __restrict__ wsrc, const int* __restrict__ wdst,
                       const int* __restrict__ csrc, const int* __restrict__ cdst,
                       int* __restrict__ cur, int* __restrict__ esrc)
{
  int t = blockIdx.x * blockDim.x + threadIdx.x;
  if (t < EW) { int p = atomicAdd(&cur[wdst[t]], 1); esrc[p] = wsrc[t] << 8; }
  if (t < EC) { int p = atomicAdd(&cur[NP + cdst[t]], 1); esrc[p] = csrc[t] << 8; }
}

// ---------- fused per-node attention: 16 lanes/node, TWO-edge cross-relation prefetch ----------
// 12 concurrent loads at wave start (q, offs, 4 esrc, 8 K/V); ~80% of all edges
// are covered by the prefetched pair per relation (deg ~Poisson(1.5)).
__global__ __launch_bounds__(256) void node_attn(
    const int* __restrict__ off, const int* __restrict__ esrc,
    const ushort_t* __restrict__ q,
    const ushort_t* __restrict__ kr_w, const ushort_t* __restrict__ vr_w,
    const ushort_t* __restrict__ kr_c, const ushort_t* __restrict__ vr_c,
    const float* __restrict__ p_rel_w, const float* __restrict__ p_rel_c,
    ushort_t* __restrict__ out_p)
{
  int gid = blockIdx.x * blockDim.x + threadIdx.x;
  int node = gid >> 4;
  int l16 = gid & 15;
  int h = l16 >> 2;
  unsigned loff = (unsigned)(l16 * 16);

  int eb0 = off[node],      ee0 = off[node + 1];
  int eb1 = off[NP + node], ee1 = off[NP + node + 1];

  uint4 qv = *(const uint4*)(q + (size_t)node * HID + l16 * 8);

  // prefetch edges 0,1 of each relation (clamped to valid index 0)
  int i0a = (eb0 < ee0) ? eb0 : 0;
  int i0b = (eb0 + 1 < ee0) ? eb0 + 1 : 0;
  int i1a = (eb1 < ee1) ? eb1 : 0;
  int i1b = (eb1 + 1 < ee1) ? eb1 + 1 : 0;
  unsigned ba0 = (unsigned)esrc[i0a] + loff;
  unsigned bb0 = (unsigned)esrc[i0b] + loff;
  unsigned ba1 = (unsigned)esrc[i1a] + loff;
  unsigned bb1 = (unsigned)esrc[i1b] + loff;
  uint4 pka[2], pva[2], pkb[2], pvb[2];
  pka[0] = *(const uint4*)((const char*)kr_w + ba0);
  pva[0] = *(const uint4*)((const char*)vr_w + ba0);
  pkb[0] = *(const uint4*)((const char*)kr_w + bb0);
  pvb[0] = *(const uint4*)((const char*)vr_w + bb0);
  pka[1] = *(const uint4*)((const char*)kr_c + ba1);
  pva[1] = *(const uint4*)((const char*)vr_c + ba1);
  pkb[1] = *(const uint4*)((const char*)kr_c + bb1);
  pvb[1] = *(const uint4*)((const char*)vr_c + bb1);

  float qf[8];
  {
    const unsigned* pq = (const unsigned*)&qv;
    #pragma unroll
    for (int w = 0; w < 4; ++w) { qf[2 * w] = bflo(pq[w]); qf[2 * w + 1] = bfhi(pq[w]); }
  }
  float prw = p_rel_w[h] * ATT_SCALE;
  float prc = p_rel_c[h] * ATT_SCALE;

  float t[8];
  #pragma unroll
  for (int i = 0; i < 8; ++i) t[i] = 0.f;

  #pragma unroll
  for (int r = 0; r < 2; ++r) {
    const char* krb = (const char*)((r == 0) ? kr_w : kr_c);
    const char* vrb = (const char*)((r == 0) ? vr_w : vr_c);
    float prr = (r == 0) ? prw : prc;
    int eb = (r == 0) ? eb0 : eb1;
    int ee = (r == 0) ? ee0 : ee1;

    float s = 0.f;
    float A[8];
    #pragma unroll
    for (int i = 0; i < 8; ++i) A[i] = 0.f;

    int e = eb;
    #pragma unroll
    for (int pf = 0; pf < 2; ++pf) {
      if (e < ee) {   // consume prefetched edge pf
        const unsigned* k8 = (const unsigned*)((pf == 0) ? &pka[r] : &pkb[r]);
        const unsigned* v8 = (const unsigned*)((pf == 0) ? &pva[r] : &pvb[r]);
        float d = 0.f;
        #pragma unroll
        for (int w = 0; w < 4; ++w) {
          d = fmaf(qf[2 * w], bflo(k8[w]), d);
          d = fmaf(qf[2 * w + 1], bfhi(k8[w]), d);
        }
        d += __shfl_xor(d, 1);
        d += __shfl_xor(d, 2);
        float p = __expf(d * prr);
        s += p;
        #pragma unroll
        for (int w = 0; w < 4; ++w) {
          A[2 * w]     = fmaf(p, bflo(v8[w]), A[2 * w]);
          A[2 * w + 1] = fmaf(p, bfhi(v8[w]), A[2 * w + 1]);
        }
        ++e;
      }
    }
    for (; e < ee; ++e) {
      unsigned kb = (unsigned)esrc[e] + loff;
      uint4 kv = *(const uint4*)(krb + kb);
      uint4 vv = *(const uint4*)(vrb + kb);
      const unsigned* k8 = (const unsigned*)&kv;
      float d = 0.f;
      #pragma unroll
      for (int w = 0; w < 4; ++w) {
        d = fmaf(qf[2 * w], bflo(k8[w]), d);
        d = fmaf(qf[2 * w + 1], bfhi(k8[w]), d);
      }
      d += __shfl_xor(d, 1);
      d += __shfl_xor(d, 2);
      float p = __expf(d * prr);
      s += p;
      const unsigned* v8 = (const unsigned*)&vv;
      #pragma unroll
      for (int w = 0; w < 4; ++w) {
        A[2 * w]     = fmaf(p, bflo(v8[w]), A[2 * w]);
        A[2 * w + 1] = fmaf(p, bfhi(v8[w]), A[2 * w + 1]);
      }
    }
    float inv = 1.0f / (s + 1e-16f);
    #pragma unroll
    for (int i = 0; i < 8; ++i) t[i] = fmaf(A[i], inv, t[i]);
  }

  uint4 o;
  unsigned* po = (unsigned*)&o;
  #pragma unroll
  for (int w = 0; w < 4; ++w) po[w] = pack2bf(t[2 * w], t[2 * w + 1]);
  *(uint4*)(out_p + (size_t)node * HID + l16 * 8) = o;
}

// ---------- MFMA epilogue: out = [gelu(outp), hp] @ Wcat^T + bo ----------
__global__ __launch_bounds__(256) void epilogue_mfma(
    const ushort_t* __restrict__ out_p, const ushort_t* __restrict__ hp,
    const ushort_t* __restrict__ Wcatb, const float* __restrict__ bo,
    float* __restrict__ out)
{
  __shared__ ushort_t As[4096];   // 512 slots x 8 = 8 KB
  const int tid  = threadIdx.x;
  const int lane = tid & 63;
  const int wv   = tid >> 6;
  const int l15  = lane & 15, kgl = lane >> 4;
  const int s2l  = (l15 ^ (l15 >> 2)) & 3;
  const int row0 = blockIdx.x * 128;

  const int r0 = tid >> 2, kgp = tid & 3;
  const int sk = kgp ^ s2row(r0);
  int g0 = row0 + r0;       if (g0 > NP - 1) g0 = NP - 1;
  int g1 = row0 + r0 + 64;  if (g1 > NP - 1) g1 = NP - 1;

  s8v bfr[8];
  #pragma unroll
  for (int ks = 0; ks < 8; ++ks)
    bfr[ks] = *(const s8v*)(Wcatb + (size_t)l15 * 256 + ks * 32 + kgl * 8);
  float bo_l = bo[l15];

  f32x4 acc[2];
  acc[0] = (f32x4){0.f, 0.f, 0.f, 0.f};
  acc[1] = (f32x4){0.f, 0.f, 0.f, 0.f};

  #pragma unroll
  for (int ph = 0; ph < 8; ++ph) {
    if (ph < 4) {
      const int kt = ph * 32;
      uint4 v0 = *(const uint4*)(out_p + (size_t)g0 * 128 + kt + sk * 8);
      uint4 v1 = *(const uint4*)(out_p + (size_t)g1 * 128 + kt + sk * 8);
      unsigned* p0 = (unsigned*)&v0;
      unsigned* p1 = (unsigned*)&v1;
      #pragma unroll
      for (int w = 0; w < 4; ++w) {
        p0[w] = cvtpk(gelu_f(bflo(p0[w])), gelu_f(bfhi(p0[w])));
        p1[w] = cvtpk(gelu_f(bflo(p1[w])), gelu_f(bfhi(p1[w])));
      }
      *(uint4*)&As[(size_t)tid * 8] = v0;
      *(uint4*)&As[(size_t)(tid + 256) * 8] = v1;
    } else {
      const int kt = (ph - 4) * 32;
      gl16(hp + (size_t)g0 * 128 + kt + sk * 8, &As[(size_t)tid * 8]);
      gl16(hp + (size_t)g1 * 128 + kt + sk * 8, &As[(size_t)(tid + 256) * 8]);
    }
    __syncthreads();

    const s8v* As8 = (const s8v*)As;
    s8v af0 = As8[(wv * 32 + l15) * 4 + (kgl ^ s2l)];
    s8v af1 = As8[(wv * 32 + 16 + l15) * 4 + (kgl ^ s2l)];
    acc[0] = __builtin_amdgcn_mfma_f32_16x16x32_bf16(af0, bfr[ph], acc[0], 0, 0, 0);
    acc[1] = __builtin_amdgcn_mfma_f32_16x16x32_bf16(af1, bfr[ph], acc[1], 0, 0, 0);
    __syncthreads();
  }

  #pragma unroll
  for (int i = 0; i < 2; ++i) {
    #pragma unroll
    for (int r = 0; r < 4; ++r) {
      int row = row0 + wv * 32 + i * 16 + kgl * 4 + r;
      if (row < NP) out[(size_t)row * NOUT + l15] = acc[i][r] + bo_l;
    }
  }
}

// ---------- launch ----------
extern "C" void kernel_launch(void* const* d_in, const int* in_sizes, int n_in,
                              void* d_out, int out_size, void* d_ws, size_t ws_size,
                              hipStream_t stream)
{
  (void)in_sizes; (void)n_in; (void)out_size; (void)ws_size;
  const float* x_paper      = (const float*)d_in[0];
  const float* x_author     = (const float*)d_in[1];
  const int*   writes_src   = (const int*)d_in[2];
  const int*   writes_dst   = (const int*)d_in[3];
  const int*   cites_src    = (const int*)d_in[4];
  const int*   cites_dst    = (const int*)d_in[5];
  const float* lin_paper_w  = (const float*)d_in[6];
  const float* lin_paper_b  = (const float*)d_in[7];
  const float* lin_author_w = (const float*)d_in[8];
  const float* lin_author_b = (const float*)d_in[9];
  const float* lin_out_w    = (const float*)d_in[10];
  const float* lin_out_b    = (const float*)d_in[11];
  const float* k_w_paper    = (const float*)d_in[12];
  const float* k_b_paper    = (const float*)d_in[13];
  const float* q_w_paper    = (const float*)d_in[14];
  const float* q_b_paper    = (const float*)d_in[15];
  const float* v_w_paper    = (const float*)d_in[16];
  const float* v_b_paper    = (const float*)d_in[17];
  const float* a_w_paper    = (const float*)d_in[18];
  const float* a_b_paper    = (const float*)d_in[19];
  const float* skip_paper   = (const float*)d_in[20];
  const float* k_w_author   = (const float*)d_in[21];
  const float* k_b_author   = (const float*)d_in[22];
  const float* v_w_author   = (const float*)d_in[25];
  const float* v_b_author   = (const float*)d_in[26];
  const float* a_rel_writes = (const float*)d_in[30];
  const float* m_rel_writes = (const float*)d_in[31];
  const float* p_rel_writes = (const float*)d_in[32];
  const float* a_rel_cites  = (const float*)d_in[33];
  const float* m_rel_cites  = (const float*)d_in[34];
  const float* p_rel_cites  = (const float*)d_in[35];

  float* ws = (float*)d_ws;
  size_t off_f = 0;
  auto nxt = [&](size_t nfloats) { float* p = ws + off_f; off_f += nfloats; return p; };
  ushort_t* hp    = (ushort_t*)nxt((size_t)NP * 64);
  ushort_t* ha    = (ushort_t*)nxt((size_t)NA * 64);
  ushort_t* qkv   = (ushort_t*)nxt((size_t)3 * NP * 64);
  ushort_t* kvw   = (ushort_t*)nxt((size_t)2 * NA * 64);
  ushort_t* outp  = (ushort_t*)nxt((size_t)NP * 64);
  int*      cnt   = (int*)nxt(SCAN_N);
  int*      offs  = (int*)nxt(SCAN_N + 2);
  int*      cur   = (int*)nxt(SCAN_N);
  int*      esrc  = (int*)nxt(EW + EC);
  int*      bsum  = (int*)nxt(512);
  ushort_t* Wall  = (ushort_t*)nxt(65536);
  float*    Ball  = nxt(5 * 128);
  ushort_t* Wcatb = (ushort_t*)nxt(2048);   // 4096 bf16
  float*    bo    = nxt(16);

  ushort_t* q_p  = qkv;
  ushort_t* kr_c = qkv + (size_t)NP * HID;
  ushort_t* vr_c = qkv + (size_t)2 * NP * HID;
  ushort_t* kr_w = kvw;
  ushort_t* vr_w = kvw + (size_t)NA * HID;

  prep_all<<<16, 256, 0, stream>>>(q_w_paper, q_b_paper,
                                   k_w_paper, k_b_paper, a_rel_cites,
                                   v_w_paper, v_b_paper, m_rel_cites,
                                   k_w_author, k_b_author, a_rel_writes,
                                   v_w_author, v_b_author, m_rel_writes,
                                   lin_paper_w, lin_author_w,
                                   a_w_paper, a_b_paper, skip_paper, lin_out_w, lin_out_b,
                                   Wall, Ball, Wcatb, bo, cnt);

  hist_k<<<(300000 + 255) / 256, 256, 0, stream>>>(writes_dst, cites_dst, cnt);
  scan1<<<SCAN_NB, SCAN_BS, 0, stream>>>(cnt, offs, bsum);
  scan2<<<1, 512, 0, stream>>>(bsum);
  scan3<<<SCAN_NB, SCAN_BS, 0, stream>>>(offs, cur, bsum);
  fill_k<<<(300000 + 255) / 256, 256, 0, stream>>>(writes_src, writes_dst,
                                                   cites_src, cites_dst, cur, esrc);

  gemm_main<<<NBP + NBA, 256, 0, stream>>>(x_paper, x_author, Wall,
                                           lin_paper_b, lin_author_b, Ball,
                                           hp, ha, qkv, kvw);

  node_attn<<<(NP * 16) / 256, 256, 0, stream>>>(
      offs, esrc, q_p, kr_w, vr_w, kr_c, vr_c, p_rel_writes, p_rel_cites, outp);

  epilogue_mfma<<<NBP, 256, 0, stream>>>(outp, hp, Wcatb, bo, (float*)d_out);
}

// Round 17
// 373.005 us; speedup vs baseline: 1.0957x; 1.0232x over previous
//
#include <hip/hip_runtime.h>
#include <cstdint>

#define NP 200000
#define NA 100000
#define EW 300000
#define EC 300000
#define HID 128
#define FIN_P 256
#define FIN_A 128
#define NOUT 16
#define ATT_SCALE 0.17677669529663687f  // 1/sqrt(32)

#define NBP 1563   // ceil(NP/128)
#define NBA 782    // ceil(NA/128)

#define SCAN_N (2 * NP)
#define SCAN_BS 256
#define SCAN_ITEMS 4
#define SCAN_TILE 1024
#define SCAN_NB ((SCAN_N + SCAN_TILE - 1) / SCAN_TILE)  // 391

typedef short s8v __attribute__((ext_vector_type(8)));
typedef float f32x4 __attribute__((ext_vector_type(4)));
typedef unsigned short ushort_t;

// ---------- helpers ----------
__device__ __forceinline__ float gelu_f(float x) {
  return 0.5f * x * (1.0f + erff(x * 0.70710678118654752f));
}
__device__ __forceinline__ ushort_t f2bf(float f) {  // RNE
  unsigned u = __float_as_uint(f);
  return (ushort_t)((u + 0x7FFFu + ((u >> 16) & 1u)) >> 16);
}
__device__ __forceinline__ unsigned pack2bf(float a, float b) {
  return (unsigned)f2bf(a) | ((unsigned)f2bf(b) << 16);
}
__device__ __forceinline__ unsigned cvtpk(float a, float b) {
  unsigned r;
  asm("v_cvt_pk_bf16_f32 %0, %1, %2" : "=v"(r) : "v"(a), "v"(b));
  return r;
}
__device__ __forceinline__ float bflo(unsigned u) { return __uint_as_float(u << 16); }
__device__ __forceinline__ float bfhi(unsigned u) { return __uint_as_float(u & 0xFFFF0000u); }

// async global->LDS, 16B/lane; LDS dest = wave-uniform base + lane*16 (linear)
__device__ __forceinline__ void gl16(const void* g, void* l) {
  __builtin_amdgcn_global_load_lds(
      (const __attribute__((address_space(1))) void*)g,
      (__attribute__((address_space(3))) void*)l, 16, 0, 0);
}

// slot swizzle: slot s holds logical (row = s>>2, kg = (s&3) ^ s2(row));
// frag read for logical (row, kgl) -> phys = row*4 + (kgl ^ s2(row)).
__device__ __forceinline__ int s2row(int r) { return (r ^ (r >> 2)) & 3; }

// ---------- prep: weights->bf16 [n][k], epilogue Wcat (bf16), cnt zeroing ----------
__global__ void prep_all(
    const float* __restrict__ qw,  const float* __restrict__ qb,
    const float* __restrict__ kwp, const float* __restrict__ kbp, const float* __restrict__ arc,
    const float* __restrict__ vwp, const float* __restrict__ vbp, const float* __restrict__ mrc,
    const float* __restrict__ kwa, const float* __restrict__ kba, const float* __restrict__ arw,
    const float* __restrict__ vwa, const float* __restrict__ vba, const float* __restrict__ mrw,
    const float* __restrict__ lpw, const float* __restrict__ law,
    const float* __restrict__ aw, const float* __restrict__ ab,
    const float* __restrict__ skip, const float* __restrict__ W2, const float* __restrict__ b2,
    ushort_t* __restrict__ Wall, float* __restrict__ Ball,
    ushort_t* __restrict__ Wcatb, float* __restrict__ bo,
    int* __restrict__ cnt)
{
  const int b = blockIdx.x, tid = threadIdx.x;
  if (b == 0) {
    for (int idx = tid; idx < 16384; idx += 256) {
      int c = idx >> 7, r = idx & 127;
      Wall[idx] = f2bf(qw[r * 128 + c]);
    }
    for (int c = tid; c < 128; c += 256) Ball[c] = qb[c];
  } else if (b <= 4) {
    const float *W, *bias, *rel;
    switch (b) {
      case 1:  W = kwp; bias = kbp; rel = arc; break;
      case 2:  W = vwp; bias = vbp; rel = mrc; break;
      case 3:  W = kwa; bias = kba; rel = arw; break;
      default: W = vwa; bias = vba; rel = mrw; break;
    }
    for (int idx = tid; idx < 16384; idx += 256) {
      int c = idx >> 7, r = idx & 127, h = c >> 5, e = c & 31;
      float s = 0.f;
      #pragma unroll
      for (int d = 0; d < 32; ++d) s += W[r * 128 + h * 32 + d] * rel[h * 1024 + d * 32 + e];
      Wall[b * 16384 + idx] = f2bf(s);
    }
    for (int c = tid; c < 128; c += 256) {
      int h = c >> 5, e = c & 31;
      float s = 0.f;
      #pragma unroll
      for (int d = 0; d < 32; ++d) s += bias[h * 32 + d] * rel[h * 1024 + d * 32 + e];
      Ball[b * 128 + c] = s;
    }
  } else if (b == 5) {
    for (int idx = tid; idx < 16384; idx += 256) {
      int c = idx >> 7, r = idx & 127;
      Wall[5 * 16384 + idx] = f2bf(law[r * 128 + c]);
    }
  } else if (b == 6) {
    for (int idx = tid; idx < 32768; idx += 256) {
      int c = idx >> 8, r = idx & 255;
      Wall[6 * 16384 + idx] = f2bf(lpw[r * 128 + c]);
    }
  } else if (b == 7) {
    float beta = 1.0f / (1.0f + expf(-skip[0]));
    for (int idx = tid; idx < 4096; idx += 256) {
      int c = idx >> 8, k = idx & 255;
      float v;
      if (k < 128) {
        float s = 0.f;
        for (int j = 0; j < 128; ++j) s += aw[k * 128 + j] * W2[j * 16 + c];
        v = beta * s;
      } else {
        v = (1.0f - beta) * W2[(k - 128) * 16 + c];
      }
      Wcatb[c * 256 + k] = f2bf(v);
    }
    if (tid < 16) {
      float s = 0.f;
      for (int k = 0; k < 128; ++k) s += ab[k] * W2[k * 16 + tid];
      bo[tid] = beta * s + b2[tid];
    }
  } else {
    int chunk = SCAN_N / 8;
    int base = (b - 8) * chunk;
    for (int i = tid; i < chunk; i += 256) cnt[base + i] = 0;
  }
}

// ---------- fused GEMM main: projection then q/kr/vr; COALESCED C-writes via LDS ----------
__global__ __launch_bounds__(256) void gemm_main(
    const float* __restrict__ xp, const float* __restrict__ xa,
    const ushort_t* __restrict__ Wall,
    const float* __restrict__ bp, const float* __restrict__ ba,
    const float* __restrict__ Ball,
    ushort_t* __restrict__ hpo, ushort_t* __restrict__ hao,
    ushort_t* __restrict__ qkv, ushort_t* __restrict__ kvw)
{
  __shared__ ushort_t As[16384];   // 32 KB
  __shared__ ushort_t Bs[16384];   // 32 KB (also reused as C-staging buffer)
  const bool isP = blockIdx.x < NBP;
  const int bid = isP ? blockIdx.x : blockIdx.x - NBP;
  const float* A = isP ? xp : xa;
  const ushort_t* Wp = Wall + (isP ? 6 * 16384 : 5 * 16384);
  const float* biasp = isP ? bp : ba;
  ushort_t* Chp = isP ? hpo : hao;
  const int M = isP ? NP : NA;
  const int KT = isP ? 256 : 128;
  const int nt = KT >> 6;
  const int base_set = isP ? 0 : 3;
  const int nsets = isP ? 3 : 2;

  const int tid  = threadIdx.x;
  const int lane = tid & 63;
  const int wv   = tid >> 6;
  const int wr   = wv >> 1, wc = wv & 1;
  const int l15  = lane & 15, kgl = lane >> 4;
  const int s2l  = (l15 ^ (l15 >> 2)) & 3;
  const int row0 = bid * 128;

  const int r0 = tid >> 2, kgp = tid & 3;
  const int sk = kgp ^ s2row(r0);
  int g0 = row0 + r0;       if (g0 > M - 1) g0 = M - 1;
  int g1 = row0 + r0 + 64;  if (g1 > M - 1) g1 = M - 1;

  // ================= part 1: input projection (BK=64 phases) =================
  {
    const float* a0p = A + (size_t)g0 * KT + sk * 8;
    const float* a1p = A + (size_t)g1 * KT + sk * 8;
    const ushort_t* b0p = Wp + (size_t)r0 * KT + sk * 8;
    const ushort_t* b1p = Wp + (size_t)(r0 + 64) * KT + sk * 8;

    f32x4 acc[4][4];
    #pragma unroll
    for (int i = 0; i < 4; ++i)
      #pragma unroll
      for (int j = 0; j < 4; ++j) acc[i][j] = (f32x4){0.f, 0.f, 0.f, 0.f};

    for (int t = 0; t < nt; ++t) {
      const int kt = t * 64;
      gl16(b0p + kt,      &Bs[(size_t)tid * 8]);
      gl16(b1p + kt,      &Bs[(size_t)(tid + 256) * 8]);
      gl16(b0p + kt + 32, &Bs[(size_t)(tid + 512) * 8]);
      gl16(b1p + kt + 32, &Bs[(size_t)(tid + 768) * 8]);
      float4 fa0 = *(const float4*)(a0p + kt);
      float4 fa1 = *(const float4*)(a0p + kt + 4);
      float4 fa2 = *(const float4*)(a1p + kt);
      float4 fa3 = *(const float4*)(a1p + kt + 4);
      float4 fb0 = *(const float4*)(a0p + kt + 32);
      float4 fb1 = *(const float4*)(a0p + kt + 36);
      float4 fb2 = *(const float4*)(a1p + kt + 32);
      float4 fb3 = *(const float4*)(a1p + kt + 36);
      uint4 v;
      v.x = cvtpk(fa0.x, fa0.y); v.y = cvtpk(fa0.z, fa0.w);
      v.z = cvtpk(fa1.x, fa1.y); v.w = cvtpk(fa1.z, fa1.w);
      *(uint4*)&As[(size_t)tid * 8] = v;
      v.x = cvtpk(fa2.x, fa2.y); v.y = cvtpk(fa2.z, fa2.w);
      v.z = cvtpk(fa3.x, fa3.y); v.w = cvtpk(fa3.z, fa3.w);
      *(uint4*)&As[(size_t)(tid + 256) * 8] = v;
      v.x = cvtpk(fb0.x, fb0.y); v.y = cvtpk(fb0.z, fb0.w);
      v.z = cvtpk(fb1.x, fb1.y); v.w = cvtpk(fb1.z, fb1.w);
      *(uint4*)&As[(size_t)(tid + 512) * 8] = v;
      v.x = cvtpk(fb2.x, fb2.y); v.y = cvtpk(fb2.z, fb2.w);
      v.z = cvtpk(fb3.x, fb3.y); v.w = cvtpk(fb3.z, fb3.w);
      *(uint4*)&As[(size_t)(tid + 768) * 8] = v;
      __syncthreads();

      const s8v* As8 = (const s8v*)As;
      const s8v* Bs8 = (const s8v*)Bs;
      #pragma unroll
      for (int pg = 0; pg < 2; ++pg) {
        s8v af[4], bfv[4];
        #pragma unroll
        for (int i = 0; i < 4; ++i)
          af[i]  = As8[pg * 512 + (wr * 64 + i * 16 + l15) * 4 + (kgl ^ s2l)];
        #pragma unroll
        for (int j = 0; j < 4; ++j)
          bfv[j] = Bs8[pg * 512 + (wc * 64 + j * 16 + l15) * 4 + (kgl ^ s2l)];
        #pragma unroll
        for (int i = 0; i < 4; ++i)
          #pragma unroll
          for (int j = 0; j < 4; ++j)
            acc[i][j] = __builtin_amdgcn_mfma_f32_16x16x32_bf16(af[i], bfv[j], acc[i][j], 0, 0, 0);
      }
      __syncthreads();
    }

    // ---- coalesced C-write: stage into Bs (swizzled), then 16B stores ----
    float bv[4];
    #pragma unroll
    for (int j = 0; j < 4; ++j) bv[j] = biasp[wc * 64 + j * 16 + l15];
    #pragma unroll
    for (int i = 0; i < 4; ++i) {
      #pragma unroll
      for (int r = 0; r < 4; ++r) {
        int row = wr * 64 + i * 16 + kgl * 4 + r;
        int o = ((row >> 2) & 3) << 3;
        #pragma unroll
        for (int j = 0; j < 4; ++j) {
          int col = wc * 64 + j * 16 + l15;
          float vv = acc[i][j][r] + bv[j];
          vv = fmaxf(vv, 0.f);
          int word = row * 64 + ((col >> 1) ^ o);
          Bs[word * 2 + (col & 1)] = f2bf(vv);
        }
      }
    }
    __syncthreads();
    {
      const unsigned* Cw = (const unsigned*)Bs;
      #pragma unroll
      for (int k = 0; k < 8; ++k) {
        int row = k * 16 + wv * 4 + (lane >> 4);
        int c16 = lane & 15;
        int word0 = row * 64 + ((c16 * 4) ^ (((row >> 2) & 3) << 3));
        uint4 vv = *(const uint4*)&Cw[word0];
        int grow = row0 + row;
        if (grow < M) *(uint4*)(Chp + (size_t)grow * 128 + c16 * 8) = vv;
      }
    }
  }
  __syncthreads();   // drain hp stores to L2 (same XCD) + free Bs

  // ================= part 2: q / kr / vr from L2-hot hp tile (A resident in As) ==========
  {
    const ushort_t* a0h = Chp + (size_t)g0 * 128 + sk * 8;
    const ushort_t* a1h = Chp + (size_t)g1 * 128 + sk * 8;
    #pragma unroll
    for (int t = 0; t < 4; ++t) {
      gl16(a0h + t * 32, &As[((size_t)t * 512 + tid) * 8]);
      gl16(a1h + t * 32, &As[((size_t)t * 512 + tid + 256) * 8]);
    }

    for (int si = 0; si < nsets; ++si) {
      const int set = base_set + si;
      const ushort_t* W = Wall + set * 16384;
      const float* bias = Ball + set * 128;
      ushort_t* C = isP ? (qkv + (size_t)set * NP * HID)
                        : (kvw + (size_t)(set - 3) * NA * HID);
      const ushort_t* b0p = W + (size_t)r0 * 128 + sk * 8;
      const ushort_t* b1p = W + (size_t)(r0 + 64) * 128 + sk * 8;
      #pragma unroll
      for (int t = 0; t < 4; ++t) {
        gl16(b0p + t * 32, &Bs[((size_t)t * 512 + tid) * 8]);
        gl16(b1p + t * 32, &Bs[((size_t)t * 512 + tid + 256) * 8]);
      }
      __syncthreads();   // A (first iter) + B staged

      f32x4 acc[4][4];
      #pragma unroll
      for (int i = 0; i < 4; ++i)
        #pragma unroll
        for (int j = 0; j < 4; ++j) acc[i][j] = (f32x4){0.f, 0.f, 0.f, 0.f};

      const s8v* As8 = (const s8v*)As;
      const s8v* Bs8 = (const s8v*)Bs;
      #pragma unroll
      for (int t = 0; t < 4; ++t) {
        s8v af[4], bfv[4];
        #pragma unroll
        for (int i = 0; i < 4; ++i)
          af[i]  = As8[t * 512 + (wr * 64 + i * 16 + l15) * 4 + (kgl ^ s2l)];
        #pragma unroll
        for (int j = 0; j < 4; ++j)
          bfv[j] = Bs8[t * 512 + (wc * 64 + j * 16 + l15) * 4 + (kgl ^ s2l)];
        #pragma unroll
        for (int i = 0; i < 4; ++i)
          #pragma unroll
          for (int j = 0; j < 4; ++j)
            acc[i][j] = __builtin_amdgcn_mfma_f32_16x16x32_bf16(af[i], bfv[j], acc[i][j], 0, 0, 0);
      }
      __syncthreads();   // all MFMA reads of Bs done before C-staging overwrites it

      // ---- coalesced C-write via Bs ----
      float bv[4];
      #pragma unroll
      for (int j = 0; j < 4; ++j) bv[j] = bias[wc * 64 + j * 16 + l15];
      #pragma unroll
      for (int i = 0; i < 4; ++i) {
        #pragma unroll
        for (int r = 0; r < 4; ++r) {
          int row = wr * 64 + i * 16 + kgl * 4 + r;
          int o = ((row >> 2) & 3) << 3;
          #pragma unroll
          for (int j = 0; j < 4; ++j) {
            int col = wc * 64 + j * 16 + l15;
            int word = row * 64 + ((col >> 1) ^ o);
            Bs[word * 2 + (col & 1)] = f2bf(acc[i][j][r] + bv[j]);
          }
        }
      }
      __syncthreads();
      {
        const unsigned* Cw = (const unsigned*)Bs;
        #pragma unroll
        for (int k = 0; k < 8; ++k) {
          int row = k * 16 + wv * 4 + (lane >> 4);
          int c16 = lane & 15;
          int word0 = row * 64 + ((c16 * 4) ^ (((row >> 2) & 3) << 3));
          uint4 vv = *(const uint4*)&Cw[word0];
          int grow = row0 + row;
          if (grow < M) *(uint4*)(C + (size_t)grow * 128 + c16 * 8) = vv;
        }
      }
      __syncthreads();   // readout done before next set's B staging
    }
  }
}

// ---------- CSR build ----------
__global__ void hist_k(const int* __restrict__ wdst, const int* __restrict__ cdst,
                       int* __restrict__ cnt)
{
  int t = blockIdx.x * blockDim.x + threadIdx.x;
  if (t < EW) atomicAdd(&cnt[wdst[t]], 1);
  if (t < EC) atomicAdd(&cnt[NP + cdst[t]], 1);
}

__global__ __launch_bounds__(SCAN_BS) void scan1(const int* __restrict__ cnt,
                                                 int* __restrict__ off,
                                                 int* __restrict__ bsum)
{
  __shared__ int sh[2][SCAN_BS];
  int tid = threadIdx.x;
  int base = blockIdx.x * SCAN_TILE + tid * SCAN_ITEMS;
  int v[SCAN_ITEMS]; int tsum = 0;
  #pragma unroll
  for (int i = 0; i < SCAN_ITEMS; ++i) {
    int idx = base + i;
    v[i] = (idx < SCAN_N) ? cnt[idx] : 0;
    tsum += v[i];
  }
  int p = 0;
  sh[0][tid] = tsum; __syncthreads();
  #pragma unroll
  for (int d = 1; d < SCAN_BS; d <<= 1) {
    int x = sh[p][tid] + ((tid >= d) ? sh[p][tid - d] : 0);
    sh[p ^ 1][tid] = x; __syncthreads(); p ^= 1;
  }
  int run = sh[p][tid] - tsum;
  #pragma unroll
  for (int i = 0; i < SCAN_ITEMS; ++i) {
    int idx = base + i;
    if (idx < SCAN_N) off[idx] = run;
    run += v[i];
  }
  if (tid == SCAN_BS - 1) bsum[blockIdx.x] = sh[p][tid];
}

__global__ __launch_bounds__(512) void scan2(int* __restrict__ bsum)
{
  __shared__ int sh[2][512];
  int tid = threadIdx.x;
  int v = (tid < SCAN_NB) ? bsum[tid] : 0;
  int p = 0;
  sh[0][tid] = v; __syncthreads();
  for (int d = 1; d < 512; d <<= 1) {
    int x = sh[p][tid] + ((tid >= d) ? sh[p][tid - d] : 0);
    sh[p ^ 1][tid] = x; __syncthreads(); p ^= 1;
  }
  if (tid < SCAN_NB) bsum[tid] = sh[p][tid] - v;
}

__global__ __launch_bounds__(SCAN_BS) void scan3(int* __restrict__ off, int* __restrict__ cur,
                                                 const int* __restrict__ bsum)
{
  int add = bsum[blockIdx.x];
  int base = blockIdx.x * SCAN_TILE + threadIdx.x;
  #pragma unroll
  for (int i = 0; i < SCAN_ITEMS; ++i) {
    int idx = base + i * SCAN_BS;
    if (idx < SCAN_N) { int t = off[idx] + add; off[idx] = t; cur[idx] = t; }
  }
  if (blockIdx.x == 0 && threadIdx.x == 0) off[SCAN_N] = EW + EC;
}

// esrc stores BYTE offsets (src * 256)
__global__ void fill_k(const int* __restrict__ wsrc, const int* __restrict__ wdst,
                       const int* __restrict__ csrc, const int* __restrict__ cdst,
                       int* __restrict__ cur, int* __restrict__ esrc)
{
  int t = blockIdx.x * blockDim.x + threadIdx.x;
  if (t < EW) { int p = atomicAdd(&cur[wdst[t]], 1); esrc[p] = wsrc[t] << 8; }
  if (t < EC) { int p = atomicAdd(&cur[NP + cdst[t]], 1); esrc[p] = csrc[t] << 8; }
}

// ---------- fused per-node attention: 16 lanes/node, TWO-edge cross-relation prefetch ----------
__global__ __launch_bounds__(256) void node_attn(
    const int* __restrict__ off, const int* __restrict__ esrc,
    const ushort_t* __restrict__ q,
    const ushort_t* __restrict__ kr_w, const ushort_t* __restrict__ vr_w,
    const ushort_t* __restrict__ kr_c, const ushort_t* __restrict__ vr_c,
    const float* __restrict__ p_rel_w, const float* __restrict__ p_rel_c,
    ushort_t* __restrict__ out_p)
{
  int gid = blockIdx.x * blockDim.x + threadIdx.x;
  int node = gid >> 4;
  int l16 = gid & 15;
  int h = l16 >> 2;
  unsigned loff = (unsigned)(l16 * 16);

  int eb0 = off[node],      ee0 = off[node + 1];
  int eb1 = off[NP + node], ee1 = off[NP + node + 1];

  uint4 qv = *(const uint4*)(q + (size_t)node * HID + l16 * 8);

  int i0a = (eb0 < ee0) ? eb0 : 0;
  int i0b = (eb0 + 1 < ee0) ? eb0 + 1 : 0;
  int i1a = (eb1 < ee1) ? eb1 : 0;
  int i1b = (eb1 + 1 < ee1) ? eb1 + 1 : 0;
  unsigned ba0 = (unsigned)esrc[i0a] + loff;
  unsigned bb0 = (unsigned)esrc[i0b] + loff;
  unsigned ba1 = (unsigned)esrc[i1a] + loff;
  unsigned bb1 = (unsigned)esrc[i1b] + loff;
  uint4 pka[2], pva[2], pkb[2], pvb[2];
  pka[0] = *(const uint4*)((const char*)kr_w + ba0);
  pva[0] = *(const uint4*)((const char*)vr_w + ba0);
  pkb[0] = *(const uint4*)((const char*)kr_w + bb0);
  pvb[0] = *(const uint4*)((const char*)vr_w + bb0);
  pka[1] = *(const uint4*)((const char*)kr_c + ba1);
  pva[1] = *(const uint4*)((const char*)vr_c + ba1);
  pkb[1] = *(const uint4*)((const char*)kr_c + bb1);
  pvb[1] = *(const uint4*)((const char*)vr_c + bb1);

  float qf[8];
  {
    const unsigned* pq = (const unsigned*)&qv;
    #pragma unroll
    for (int w = 0; w < 4; ++w) { qf[2 * w] = bflo(pq[w]); qf[2 * w + 1] = bfhi(pq[w]); }
  }
  float prw = p_rel_w[h] * ATT_SCALE;
  float prc = p_rel_c[h] * ATT_SCALE;

  float t[8];
  #pragma unroll
  for (int i = 0; i < 8; ++i) t[i] = 0.f;

  #pragma unroll
  for (int r = 0; r < 2; ++r) {
    const char* krb = (const char*)((r == 0) ? kr_w : kr_c);
    const char* vrb = (const char*)((r == 0) ? vr_w : vr_c);
    float prr = (r == 0) ? prw : prc;
    int eb = (r == 0) ? eb0 : eb1;
    int ee = (r == 0) ? ee0 : ee1;

    float s = 0.f;
    float A[8];
    #pragma unroll
    for (int i = 0; i < 8; ++i) A[i] = 0.f;

    int e = eb;
    #pragma unroll
    for (int pf = 0; pf < 2; ++pf) {
      if (e < ee) {
        const unsigned* k8 = (const unsigned*)((pf == 0) ? &pka[r] : &pkb[r]);
        const unsigned* v8 = (const unsigned*)((pf == 0) ? &pva[r] : &pvb[r]);
        float d = 0.f;
        #pragma unroll
        for (int w = 0; w < 4; ++w) {
          d = fmaf(qf[2 * w], bflo(k8[w]), d);
          d = fmaf(qf[2 * w + 1], bfhi(k8[w]), d);
        }
        d += __shfl_xor(d, 1);
        d += __shfl_xor(d, 2);
        float p = __expf(d * prr);
        s += p;
        #pragma unroll
        for (int w = 0; w < 4; ++w) {
          A[2 * w]     = fmaf(p, bflo(v8[w]), A[2 * w]);
          A[2 * w + 1] = fmaf(p, bfhi(v8[w]), A[2 * w + 1]);
        }
        ++e;
      }
    }
    for (; e < ee; ++e) {
      unsigned kb = (unsigned)esrc[e] + loff;
      uint4 kv = *(const uint4*)(krb + kb);
      uint4 vv = *(const uint4*)(vrb + kb);
      const unsigned* k8 = (const unsigned*)&kv;
      float d = 0.f;
      #pragma unroll
      for (int w = 0; w < 4; ++w) {
        d = fmaf(qf[2 * w], bflo(k8[w]), d);
        d = fmaf(qf[2 * w + 1], bfhi(k8[w]), d);
      }
      d += __shfl_xor(d, 1);
      d += __shfl_xor(d, 2);
      float p = __expf(d * prr);
      s += p;
      const unsigned* v8 = (const unsigned*)&vv;
      #pragma unroll
      for (int w = 0; w < 4; ++w) {
        A[2 * w]     = fmaf(p, bflo(v8[w]), A[2 * w]);
        A[2 * w + 1] = fmaf(p, bfhi(v8[w]), A[2 * w + 1]);
      }
    }
    float inv = 1.0f / (s + 1e-16f);
    #pragma unroll
    for (int i = 0; i < 8; ++i) t[i] = fmaf(A[i], inv, t[i]);
  }

  uint4 o;
  unsigned* po = (unsigned*)&o;
  #pragma unroll
  for (int w = 0; w < 4; ++w) po[w] = pack2bf(t[2 * w], t[2 * w + 1]);
  *(uint4*)(out_p + (size_t)node * HID + l16 * 8) = o;
}

// ---------- MFMA epilogue: out = [gelu(outp), hp] @ Wcat^T + bo ----------
__global__ __launch_bounds__(256) void epilogue_mfma(
    const ushort_t* __restrict__ out_p, const ushort_t* __restrict__ hp,
    const ushort_t* __restrict__ Wcatb, const float* __restrict__ bo,
    float* __restrict__ out)
{
  __shared__ ushort_t As[4096];   // 512 slots x 8 = 8 KB
  const int tid  = threadIdx.x;
  const int lane = tid & 63;
  const int wv   = tid >> 6;
  const int l15  = lane & 15, kgl = lane >> 4;
  const int s2l  = (l15 ^ (l15 >> 2)) & 3;
  const int row0 = blockIdx.x * 128;

  const int r0 = tid >> 2, kgp = tid & 3;
  const int sk = kgp ^ s2row(r0);
  int g0 = row0 + r0;       if (g0 > NP - 1) g0 = NP - 1;
  int g1 = row0 + r0 + 64;  if (g1 > NP - 1) g1 = NP - 1;

  s8v bfr[8];
  #pragma unroll
  for (int ks = 0; ks < 8; ++ks)
    bfr[ks] = *(const s8v*)(Wcatb + (size_t)l15 * 256 + ks * 32 + kgl * 8);
  float bo_l = bo[l15];

  f32x4 acc[2];
  acc[0] = (f32x4){0.f, 0.f, 0.f, 0.f};
  acc[1] = (f32x4){0.f, 0.f, 0.f, 0.f};

  #pragma unroll
  for (int ph = 0; ph < 8; ++ph) {
    if (ph < 4) {
      const int kt = ph * 32;
      uint4 v0 = *(const uint4*)(out_p + (size_t)g0 * 128 + kt + sk * 8);
      uint4 v1 = *(const uint4*)(out_p + (size_t)g1 * 128 + kt + sk * 8);
      unsigned* p0 = (unsigned*)&v0;
      unsigned* p1 = (unsigned*)&v1;
      #pragma unroll
      for (int w = 0; w < 4; ++w) {
        p0[w] = cvtpk(gelu_f(bflo(p0[w])), gelu_f(bfhi(p0[w])));
        p1[w] = cvtpk(gelu_f(bflo(p1[w])), gelu_f(bfhi(p1[w])));
      }
      *(uint4*)&As[(size_t)tid * 8] = v0;
      *(uint4*)&As[(size_t)(tid + 256) * 8] = v1;
    } else {
      const int kt = (ph - 4) * 32;
      gl16(hp + (size_t)g0 * 128 + kt + sk * 8, &As[(size_t)tid * 8]);
      gl16(hp + (size_t)g1 * 128 + kt + sk * 8, &As[(size_t)(tid + 256) * 8]);
    }
    __syncthreads();

    const s8v* As8 = (const s8v*)As;
    s8v af0 = As8[(wv * 32 + l15) * 4 + (kgl ^ s2l)];
    s8v af1 = As8[(wv * 32 + 16 + l15) * 4 + (kgl ^ s2l)];
    acc[0] = __builtin_amdgcn_mfma_f32_16x16x32_bf16(af0, bfr[ph], acc[0], 0, 0, 0);
    acc[1] = __builtin_amdgcn_mfma_f32_16x16x32_bf16(af1, bfr[ph], acc[1], 0, 0, 0);
    __syncthreads();
  }

  #pragma unroll
  for (int i = 0; i < 2; ++i) {
    #pragma unroll
    for (int r = 0; r < 4; ++r) {
      int row = row0 + wv * 32 + i * 16 + kgl * 4 + r;
      if (row < NP) out[(size_t)row * NOUT + l15] = acc[i][r] + bo_l;
    }
  }
}

// ---------- launch ----------
extern "C" void kernel_launch(void* const* d_in, const int* in_sizes, int n_in,
                              void* d_out, int out_size, void* d_ws, size_t ws_size,
                              hipStream_t stream)
{
  (void)in_sizes; (void)n_in; (void)out_size; (void)ws_size;
  const float* x_paper      = (const float*)d_in[0];
  const float* x_author     = (const float*)d_in[1];
  const int*   writes_src   = (const int*)d_in[2];
  const int*   writes_dst   = (const int*)d_in[3];
  const int*   cites_src    = (const int*)d_in[4];
  const int*   cites_dst    = (const int*)d_in[5];
  const float* lin_paper_w  = (const float*)d_in[6];
  const float* lin_paper_b  = (const float*)d_in[7];
  const float* lin_author_w = (const float*)d_in[8];
  const float* lin_author_b = (const float*)d_in[9];
  const float* lin_out_w    = (const float*)d_in[10];
  const float* lin_out_b    = (const float*)d_in[11];
  const float* k_w_paper    = (const float*)d_in[12];
  const float* k_b_paper    = (const float*)d_in[13];
  const float* q_w_paper    = (const float*)d_in[14];
  const float* q_b_paper    = (const float*)d_in[15];
  const float* v_w_paper    = (const float*)d_in[16];
  const float* v_b_paper    = (const float*)d_in[17];
  const float* a_w_paper    = (const float*)d_in[18];
  const float* a_b_paper    = (const float*)d_in[19];
  const float* skip_paper   = (const float*)d_in[20];
  const float* k_w_author   = (const float*)d_in[21];
  const float* k_b_author   = (const float*)d_in[22];
  const float* v_w_author   = (const float*)d_in[25];
  const float* v_b_author   = (const float*)d_in[26];
  const float* a_rel_writes = (const float*)d_in[30];
  const float* m_rel_writes = (const float*)d_in[31];
  const float* p_rel_writes = (const float*)d_in[32];
  const float* a_rel_cites  = (const float*)d_in[33];
  const float* m_rel_cites  = (const float*)d_in[34];
  const float* p_rel_cites  = (const float*)d_in[35];

  float* ws = (float*)d_ws;
  size_t off_f = 0;
  auto nxt = [&](size_t nfloats) { float* p = ws + off_f; off_f += nfloats; return p; };
  ushort_t* hp    = (ushort_t*)nxt((size_t)NP * 64);
  ushort_t* ha    = (ushort_t*)nxt((size_t)NA * 64);
  ushort_t* qkv   = (ushort_t*)nxt((size_t)3 * NP * 64);
  ushort_t* kvw   = (ushort_t*)nxt((size_t)2 * NA * 64);
  ushort_t* outp  = (ushort_t*)nxt((size_t)NP * 64);
  int*      cnt   = (int*)nxt(SCAN_N);
  int*      offs  = (int*)nxt(SCAN_N + 2);
  int*      cur   = (int*)nxt(SCAN_N);
  int*      esrc  = (int*)nxt(EW + EC);
  int*      bsum  = (int*)nxt(512);
  ushort_t* Wall  = (ushort_t*)nxt(65536);
  float*    Ball  = nxt(5 * 128);
  ushort_t* Wcatb = (ushort_t*)nxt(2048);   // 4096 bf16
  float*    bo    = nxt(16);

  ushort_t* q_p  = qkv;
  ushort_t* kr_c = qkv + (size_t)NP * HID;
  ushort_t* vr_c = qkv + (size_t)2 * NP * HID;
  ushort_t* kr_w = kvw;
  ushort_t* vr_w = kvw + (size_t)NA * HID;

  prep_all<<<16, 256, 0, stream>>>(q_w_paper, q_b_paper,
                                   k_w_paper, k_b_paper, a_rel_cites,
                                   v_w_paper, v_b_paper, m_rel_cites,
                                   k_w_author, k_b_author, a_rel_writes,
                                   v_w_author, v_b_author, m_rel_writes,
                                   lin_paper_w, lin_author_w,
                                   a_w_paper, a_b_paper, skip_paper, lin_out_w, lin_out_b,
                                   Wall, Ball, Wcatb, bo, cnt);

  hist_k<<<(300000 + 255) / 256, 256, 0, stream>>>(writes_dst, cites_dst, cnt);
  scan1<<<SCAN_NB, SCAN_BS, 0, stream>>>(cnt, offs, bsum);
  scan2<<<1, 512, 0, stream>>>(bsum);
  scan3<<<SCAN_NB, SCAN_BS, 0, stream>>>(offs, cur, bsum);
  fill_k<<<(300000 + 255) / 256, 256, 0, stream>>>(writes_src, writes_dst,
                                                   cites_src, cites_dst, cur, esrc);

  gemm_main<<<NBP + NBA, 256, 0, stream>>>(x_paper, x_author, Wall,
                                           lin_paper_b, lin_author_b, Ball,
                                           hp, ha, qkv, kvw);

  node_attn<<<(NP * 16) / 256, 256, 0, stream>>>(
      offs, esrc, q_p, kr_w, vr_w, kr_c, vr_c, p_rel_writes, p_rel_cites, outp);

  epilogue_mfma<<<NBP, 256, 0, stream>>>(outp, hp, Wcatb, bo, (float*)d_out);
}